// Round 5
// baseline (912.159 us; speedup 1.0000x reference)
//
#include <hip/hip_runtime.h>
#include <hip/hip_fp16.h>

#define BEPS 1e-5f
static constexpr int TPB = 256;
static constexpr int G_SC = 512;      // scatter workgroups
static constexpr int BK_SHIFT = 8;    // bucket = 256-node range
static constexpr int BK_NODES = 256;
static constexpr int KMAX = 512;      // max buckets (N <= 131072)

union F4H8 { float4 f4; __half2 h2[4]; };  // 16B = 8 halfs

typedef _Float16 half8 __attribute__((ext_vector_type(8)));
typedef float floatx4 __attribute__((ext_vector_type(4)));

// ================= CSR build: two-level bucket counting sort =================

__global__ __launch_bounds__(TPB) void k_zero_int(int* __restrict__ p, int n) {
  int i = blockIdx.x * TPB + threadIdx.x;
  if (i < n) p[i] = 0;
}

__global__ __launch_bounds__(TPB) void k_hist(const int* __restrict__ dst,
                                              int* __restrict__ histG,
                                              int* __restrict__ btot,
                                              int E, int K, int chunk) {
  __shared__ int lh[KMAX];
  int g = blockIdx.x, t = threadIdx.x;
  for (int i = t; i < KMAX; i += TPB) lh[i] = 0;
  __syncthreads();
  int e0 = g * chunk, e1 = min(E, e0 + chunk);
  for (int e = e0 + t; e < e1; e += TPB) atomicAdd(&lh[dst[e] >> BK_SHIFT], 1);
  __syncthreads();
  for (int i = t; i < K; i += TPB) {
    histG[i * G_SC + g] = lh[i];
    atomicAdd(&btot[i], lh[i]);
  }
}

__global__ __launch_bounds__(KMAX) void k_bbase(const int* __restrict__ btot,
                                                int* __restrict__ bbase, int K) {
  __shared__ int sh[KMAX];
  int t = threadIdx.x;
  int v = (t < K) ? btot[t] : 0;
  sh[t] = v;
  __syncthreads();
  for (int s = 1; s < KMAX; s <<= 1) {
    int x = sh[t];
    int y = (t >= s) ? sh[t - s] : 0;
    __syncthreads();
    sh[t] = x + y;
    __syncthreads();
  }
  if (t < K) bbase[t] = sh[t] - v;
  if (t == 0) bbase[K] = sh[K - 1];
}

__global__ __launch_bounds__(G_SC) void k_offs(const int* __restrict__ histG,
                                               const int* __restrict__ bbase,
                                               int* __restrict__ offs) {
  __shared__ int sh[G_SC];
  int b = blockIdx.x, t = threadIdx.x;
  int v = histG[b * G_SC + t];
  sh[t] = v;
  __syncthreads();
  for (int s = 1; s < G_SC; s <<= 1) {
    int x = sh[t];
    int y = (t >= s) ? sh[t - s] : 0;
    __syncthreads();
    sh[t] = x + y;
    __syncthreads();
  }
  offs[b * G_SC + t] = bbase[b] + sh[t] - v;
}

__global__ __launch_bounds__(TPB) void k_scatter(const int* __restrict__ src,
                                                 const int* __restrict__ dst,
                                                 const int* __restrict__ offs,
                                                 unsigned int* __restrict__ pairs,
                                                 int E, int K, int chunk) {
  __shared__ int cur[KMAX];
  int g = blockIdx.x, t = threadIdx.x;
  for (int i = t; i < K; i += TPB) cur[i] = offs[i * G_SC + g];
  __syncthreads();
  int e0 = g * chunk, e1 = min(E, e0 + chunk);
  for (int e = e0 + t; e < e1; e += TPB) {
    int d = dst[e];
    int b = d >> BK_SHIFT;
    int pos = atomicAdd(&cur[b], 1);
    pairs[pos] = (unsigned int)src[e] | ((unsigned int)(d & (BK_NODES - 1)) << 20);
  }
}

// per-bucket LDS counting sort -> colidx, rowptr, dinv; also global degree hist
__global__ __launch_bounds__(TPB) void k_bucket_sort(const unsigned int* __restrict__ pairs,
                                                     const int* __restrict__ bbase,
                                                     int* __restrict__ rowptr,
                                                     int* __restrict__ colidx,
                                                     float* __restrict__ dinv,
                                                     int* __restrict__ dhist,
                                                     int N, int E) {
  __shared__ int deg[BK_NODES];
  __shared__ int sh[BK_NODES];
  int b = blockIdx.x, t = threadIdx.x;
  int base = bbase[b], end = bbase[b + 1];
  int n0 = b << BK_SHIFT;
  int nNodes = min(BK_NODES, N - n0);
  deg[t] = 0;
  __syncthreads();
  for (int e = base + t; e < end; e += TPB) atomicAdd(&deg[pairs[e] >> 20], 1);
  __syncthreads();
  int v = deg[t];
  sh[t] = v;
  __syncthreads();
  for (int s = 1; s < TPB; s <<= 1) {
    int x = sh[t];
    int y = (t >= s) ? sh[t - s] : 0;
    __syncthreads();
    sh[t] = x + y;
    __syncthreads();
  }
  int excl = sh[t] - v;
  if (t < nNodes) {
    rowptr[n0 + t] = base + excl;
    dinv[n0 + t] = rsqrtf((float)(v + 1));
    atomicAdd(&dhist[min(v, 63)], 1);  // degree histogram for sorted schedule
  }
  if (b == (int)gridDim.x - 1 && t == 0) rowptr[N] = E;
  __syncthreads();
  deg[t] = excl;  // reuse as cursor
  __syncthreads();
  for (int e = base + t; e < end; e += TPB) {
    unsigned int p = pairs[e];
    int pos = atomicAdd(&deg[p >> 20], 1);
    colidx[base + pos] = (int)(p & 0xFFFFFu);
  }
}

// descending (suffix) exclusive scan of 64 degree bins -> dcur
__global__ __launch_bounds__(64) void k_degbase(const int* __restrict__ dhist,
                                                int* __restrict__ dcur) {
  __shared__ int sh[64];
  int t = threadIdx.x;
  sh[t] = dhist[t];
  __syncthreads();
  if (t == 0) {
    int acc = 0;
    for (int d = 63; d >= 0; --d) { int c = sh[d]; sh[d] = acc; acc += c; }
  }
  __syncthreads();
  dcur[t] = sh[t];
}

// scatter node ids into degree-sorted (descending) order[]
__global__ __launch_bounds__(TPB) void k_degscatter(const int* __restrict__ rowptr,
                                                    int* __restrict__ dcur,
                                                    int* __restrict__ order, int N) {
  int i = blockIdx.x * TPB + threadIdx.x;
  if (i >= N) return;
  int d = min(rowptr[i + 1] - rowptr[i], 63);
  int pos = atomicAdd(&dcur[d], 1);
  order[pos] = i;
}

// ================= W pack (all 5 weights, one launch) =================
__device__ inline void packone(const float* __restrict__ W, _Float16* __restrict__ Wp,
                               int i, int FO) {
  int j = i & 7, lane = (i >> 3) & 63, tile = i >> 9;
  int nct = FO >> 4, ct = tile % nct, kch = tile / nct;
  int k = kch * 32 + ((lane >> 4) << 3) + j;
  int n = (ct << 4) + (lane & 15);
  Wp[i] = (_Float16)W[k * FO + n];
}

__global__ __launch_bounds__(TPB) void k_packAll(const float* w1, _Float16* p1,
                                                 const float* w2, _Float16* p2,
                                                 const float* w3, _Float16* p3,
                                                 const float* w4, _Float16* p4,
                                                 const float* w5, _Float16* p5) {
  int i = blockIdx.x * TPB + threadIdx.x;
  if (i < 8192) packone(w1, p1, i, 64);
  else if (i < 16384) packone(w2, p2, i - 8192, 128);
  else if (i < 24576) packone(w3, p3, i - 16384, 64);
  else if (i < 26624) packone(w4, p4, i - 24576, 32);
  else if (i < 27136) packone(w5, p5, i - 26624, 16);
}

// ================= MFMA GEMM =================
// Block = 4 waves; wave computes 16 rows x FO via v_mfma_f32_16x16x32_f16.
// EPI 0: out = acc*dinv[row] (fp16)   EPI 1: out = relu(bn(acc+bias)) (fp16)
template <int FI, int FO, int EPI, bool F32IN>
__global__ __launch_bounds__(TPB) void k_mgemm(const void* __restrict__ hin,
                                               const _Float16* __restrict__ Wp,
                                               const float* __restrict__ dinv,
                                               const float* __restrict__ bias,
                                               const float* __restrict__ g,
                                               const float* __restrict__ be,
                                               const float* __restrict__ m,
                                               const float* __restrict__ v,
                                               __half* __restrict__ out, int N) {
  constexpr int NCT = FO / 16;
  constexpr int NKC = FI / 32;
  __shared__ float4 Wsh[NKC * NCT * 64];
  for (int i = threadIdx.x; i < NKC * NCT * 64; i += TPB)
    Wsh[i] = reinterpret_cast<const float4*>(Wp)[i];
  __syncthreads();

  int lane = threadIdx.x & 63;
  int wv = threadIdx.x >> 6;
  int quad = lane >> 4;
  int rowBase = blockIdx.x * 64 + wv * 16;
  int rA = min(rowBase + (lane & 15), N - 1);

  floatx4 acc[NCT];
#pragma unroll
  for (int ct = 0; ct < NCT; ++ct) acc[ct] = (floatx4){0.f, 0.f, 0.f, 0.f};

#pragma unroll
  for (int kch = 0; kch < NKC; ++kch) {
    half8 a;
    if constexpr (F32IN) {
      const float4* xp = reinterpret_cast<const float4*>(hin);
      size_t idx = ((size_t)rA * FI + kch * 32 + quad * 8) >> 2;
      float4 fa = xp[idx], fb = xp[idx + 1];
      a[0] = (_Float16)fa.x; a[1] = (_Float16)fa.y; a[2] = (_Float16)fa.z; a[3] = (_Float16)fa.w;
      a[4] = (_Float16)fb.x; a[5] = (_Float16)fb.y; a[6] = (_Float16)fb.z; a[7] = (_Float16)fb.w;
    } else {
      union { float4 f4; half8 h8; } ua;
      ua.f4 = reinterpret_cast<const float4*>(hin)[((size_t)rA * FI + kch * 32 + quad * 8) >> 3];
      a = ua.h8;
    }
#pragma unroll
    for (int ct = 0; ct < NCT; ++ct) {
      union { float4 f4; half8 h8; } ub;
      ub.f4 = Wsh[(kch * NCT + ct) * 64 + lane];
      acc[ct] = __builtin_amdgcn_mfma_f32_16x16x32_f16(a, ub.h8, acc[ct], 0, 0, 0);
    }
  }

  int r0 = rowBase + quad * 4;
  if (EPI == 0) {
    float dv[4];
#pragma unroll
    for (int reg = 0; reg < 4; ++reg) dv[reg] = (r0 + reg < N) ? dinv[r0 + reg] : 0.f;
#pragma unroll
    for (int ct = 0; ct < NCT; ++ct) {
      int col = ct * 16 + (lane & 15);
#pragma unroll
      for (int reg = 0; reg < 4; ++reg) {
        int r = r0 + reg;
        if (r < N) out[(size_t)r * FO + col] = __float2half(acc[ct][reg] * dv[reg]);
      }
    }
  } else {
#pragma unroll
    for (int ct = 0; ct < NCT; ++ct) {
      int col = ct * 16 + (lane & 15);
      float sc = g[col] * rsqrtf(v[col] + BEPS);
      float bb = bias[col] - m[col];
      float ee = be[col];
#pragma unroll
      for (int reg = 0; reg < 4; ++reg) {
        int r = r0 + reg;
        if (r < N) out[(size_t)r * FO + col] = __float2half(fmaxf((acc[ct][reg] + bb) * sc + ee, 0.f));
      }
    }
  }
}

// ================= Aggregation (fp16 in, f32 accumulate) =================
// Processes nodes in degree-sorted order[] so a wave's nodes have ~equal
// degree (kills lockstep divergence). Edge loop unrolled 8x for MLP.
// MODE 0: val+bias (TO=float, final)  MODE 1: relu(bn(val+bias))
// MODE 2: relu(bn(val+bias))*dinv     MODE 3: val (pre-GEMM agg)
template <int F, int MODE, typename TO>
__global__ __launch_bounds__(TPB) void k_agg(const __half* __restrict__ in,
                                             const int* __restrict__ rowptr,
                                             const int* __restrict__ colidx,
                                             const int* __restrict__ order,
                                             const float* __restrict__ dinv,
                                             const float* __restrict__ bias,
                                             const float* __restrict__ g,
                                             const float* __restrict__ be,
                                             const float* __restrict__ m,
                                             const float* __restrict__ v,
                                             TO* __restrict__ out, int N) {
  constexpr int V = F / 8;
  constexpr int NPB = TPB / V;
  int gidx = blockIdx.x * NPB + (int)(threadIdx.x / V);
  int lane = threadIdx.x % V;
  if (gidx >= N) return;
  int node = order[gidx];
  const float4* in16 = reinterpret_cast<const float4*>(in);
  const size_t rs = F / 8;
  float acc[8];
  {
    F4H8 u;
    u.f4 = in16[(size_t)node * rs + lane];
#pragma unroll
    for (int i = 0; i < 4; ++i) {
      float2 t2 = __half22float2(u.h2[i]);
      acc[2 * i] = t2.x;
      acc[2 * i + 1] = t2.y;
    }
  }
  int e0 = rowptr[node], e1 = rowptr[node + 1];
  int e = e0;
  for (; e + 8 <= e1; e += 8) {
    int s[8];
#pragma unroll
    for (int q = 0; q < 8; ++q) s[q] = colidx[e + q];
    F4H8 u[8];
#pragma unroll
    for (int q = 0; q < 8; ++q) u[q].f4 = in16[(size_t)s[q] * rs + lane];
#pragma unroll
    for (int q = 0; q < 8; ++q) {
#pragma unroll
      for (int i = 0; i < 4; ++i) {
        float2 t2 = __half22float2(u[q].h2[i]);
        acc[2 * i] += t2.x;
        acc[2 * i + 1] += t2.y;
      }
    }
  }
  for (; e + 4 <= e1; e += 4) {
    int s0 = colidx[e + 0], s1 = colidx[e + 1], s2 = colidx[e + 2], s3 = colidx[e + 3];
    F4H8 u0, u1, u2, u3;
    u0.f4 = in16[(size_t)s0 * rs + lane];
    u1.f4 = in16[(size_t)s1 * rs + lane];
    u2.f4 = in16[(size_t)s2 * rs + lane];
    u3.f4 = in16[(size_t)s3 * rs + lane];
#pragma unroll
    for (int i = 0; i < 4; ++i) {
      float2 a = __half22float2(u0.h2[i]), b = __half22float2(u1.h2[i]);
      float2 c = __half22float2(u2.h2[i]), d = __half22float2(u3.h2[i]);
      acc[2 * i] += (a.x + b.x) + (c.x + d.x);
      acc[2 * i + 1] += (a.y + b.y) + (c.y + d.y);
    }
  }
  for (; e < e1; ++e) {
    F4H8 u;
    u.f4 = in16[(size_t)colidx[e] * rs + lane];
#pragma unroll
    for (int i = 0; i < 4; ++i) {
      float2 t2 = __half22float2(u.h2[i]);
      acc[2 * i] += t2.x;
      acc[2 * i + 1] += t2.y;
    }
  }
  float dv = dinv[node];
#pragma unroll
  for (int i = 0; i < 8; ++i) acc[i] *= dv;
  if (MODE == 0) {
    float4 ba = reinterpret_cast<const float4*>(bias)[lane * 2];
    float4 bb = reinterpret_cast<const float4*>(bias)[lane * 2 + 1];
    acc[0] += ba.x; acc[1] += ba.y; acc[2] += ba.z; acc[3] += ba.w;
    acc[4] += bb.x; acc[5] += bb.y; acc[6] += bb.z; acc[7] += bb.w;
  } else if (MODE == 1 || MODE == 2) {
    const float4* B = reinterpret_cast<const float4*>(bias);
    const float4* G = reinterpret_cast<const float4*>(g);
    const float4* Be = reinterpret_cast<const float4*>(be);
    const float4* M = reinterpret_cast<const float4*>(m);
    const float4* Vv = reinterpret_cast<const float4*>(v);
#pragma unroll
    for (int h = 0; h < 2; ++h) {
      float4 b4 = B[lane * 2 + h], g4 = G[lane * 2 + h], e4 = Be[lane * 2 + h];
      float4 m4 = M[lane * 2 + h], v4 = Vv[lane * 2 + h];
      float* a = acc + 4 * h;
      a[0] = fmaxf((a[0] + b4.x - m4.x) * (g4.x * rsqrtf(v4.x + BEPS)) + e4.x, 0.f);
      a[1] = fmaxf((a[1] + b4.y - m4.y) * (g4.y * rsqrtf(v4.y + BEPS)) + e4.y, 0.f);
      a[2] = fmaxf((a[2] + b4.z - m4.z) * (g4.z * rsqrtf(v4.z + BEPS)) + e4.z, 0.f);
      a[3] = fmaxf((a[3] + b4.w - m4.w) * (g4.w * rsqrtf(v4.w + BEPS)) + e4.w, 0.f);
    }
    if (MODE == 2) {
#pragma unroll
      for (int i = 0; i < 8; ++i) acc[i] *= dv;
    }
  }
  if constexpr (sizeof(TO) == 2) {
    F4H8 u;
#pragma unroll
    for (int i = 0; i < 4; ++i) u.h2[i] = __floats2half2_rn(acc[2 * i], acc[2 * i + 1]);
    reinterpret_cast<float4*>(out)[(size_t)node * rs + lane] = u.f4;
  } else {
    float4 o0 = {acc[0], acc[1], acc[2], acc[3]};
    float4 o1 = {acc[4], acc[5], acc[6], acc[7]};
    float4* op = reinterpret_cast<float4*>((float*)out + (size_t)node * F + lane * 8);
    op[0] = o0;
    op[1] = o1;
  }
}

// ================= launch =================

extern "C" void kernel_launch(void* const* d_in, const int* in_sizes, int n_in,
                              void* d_out, int out_size, void* d_ws, size_t ws_size,
                              hipStream_t stream) {
  const float* x = (const float*)d_in[0];
  const int* ei = (const int*)d_in[1];
  const int N = in_sizes[0] / 128;
  const int E = in_sizes[1] / 2;
  const int* src = ei;
  const int* dst = ei + E;

  const float* w1 = (const float*)d_in[2];  const float* b1 = (const float*)d_in[3];
  const float* w2 = (const float*)d_in[4];  const float* b2 = (const float*)d_in[5];
  const float* w3 = (const float*)d_in[6];  const float* b3 = (const float*)d_in[7];
  const float* w4 = (const float*)d_in[8];  const float* b4 = (const float*)d_in[9];
  const float* w5 = (const float*)d_in[10]; const float* b5 = (const float*)d_in[11];
  const float* g1 = (const float*)d_in[12]; const float* be1 = (const float*)d_in[13];
  const float* m1 = (const float*)d_in[14]; const float* v1 = (const float*)d_in[15];
  const float* g2 = (const float*)d_in[16]; const float* be2 = (const float*)d_in[17];
  const float* m2 = (const float*)d_in[18]; const float* v2 = (const float*)d_in[19];
  const float* g3 = (const float*)d_in[20]; const float* be3 = (const float*)d_in[21];
  const float* m3 = (const float*)d_in[22]; const float* v3 = (const float*)d_in[23];
  const float* g4 = (const float*)d_in[24]; const float* be4 = (const float*)d_in[25];
  const float* m4 = (const float*)d_in[26]; const float* v4 = (const float*)d_in[27];
  float* out = (float*)d_out;

  char* ws = (char*)d_ws;
  size_t off = 0;
  auto alloc = [&](size_t bytes) -> void* {
    void* p = ws + off;
    off += (bytes + 255) & ~(size_t)255;
    return p;
  };
  float*        dinv   = (float*)alloc((size_t)N * 4);
  int*          rowptr = (int*)alloc((size_t)(N + 1) * 4);
  int*          colidx = (int*)alloc((size_t)E * 4);
  unsigned int* pairs  = (unsigned int*)alloc((size_t)E * 4);
  int*          histG  = (int*)alloc((size_t)KMAX * G_SC * 4);
  int*          offs   = (int*)alloc((size_t)KMAX * G_SC * 4);
  int*          btot   = (int*)alloc(KMAX * 4);       // KMAX*4 = 2048, 256-aligned:
  int*          dhist  = (int*)alloc(64 * 4);         // contiguous with btot
  int*          dcur   = (int*)alloc(64 * 4);
  int*          order  = (int*)alloc((size_t)N * 4);
  int*          bbase  = (int*)alloc((KMAX + 1) * 4);
  _Float16*     wp1    = (_Float16*)alloc(128 * 64 * 2);
  _Float16*     wp2    = (_Float16*)alloc(64 * 128 * 2);
  _Float16*     wp3    = (_Float16*)alloc(128 * 64 * 2);
  _Float16*     wp4    = (_Float16*)alloc(64 * 32 * 2);
  _Float16*     wp5    = (_Float16*)alloc(32 * 16 * 2);
  __half*       bufA   = (__half*)alloc((size_t)N * 128 * 2);
  __half*       bufB   = (__half*)alloc((size_t)N * 128 * 2);
  (void)ws_size; (void)n_in; (void)out_size;

  const int K = (N + BK_NODES - 1) >> BK_SHIFT;  // 391 for N=100000
  const int chunk = (E + G_SC - 1) / G_SC;

  // CSR build + degree-sorted schedule
  k_zero_int<<<3, TPB, 0, stream>>>(btot, KMAX + 64);  // btot + dhist (contiguous)
  k_hist<<<G_SC, TPB, 0, stream>>>(dst, histG, btot, E, K, chunk);
  k_bbase<<<1, KMAX, 0, stream>>>(btot, bbase, K);
  k_offs<<<K, G_SC, 0, stream>>>(histG, bbase, offs);
  k_scatter<<<G_SC, TPB, 0, stream>>>(src, dst, offs, pairs, E, K, chunk);
  k_bucket_sort<<<K, TPB, 0, stream>>>(pairs, bbase, rowptr, colidx, dinv, dhist, N, E);
  k_degbase<<<1, 64, 0, stream>>>(dhist, dcur);
  k_degscatter<<<(N + TPB - 1) / TPB, TPB, 0, stream>>>(rowptr, dcur, order, N);

  // pack all weights into MFMA B-fragment layout (one launch)
  k_packAll<<<(27136 + TPB - 1) / TPB, TPB, 0, stream>>>(w1, wp1, w2, wp2, w3, wp3, w4, wp4, w5, wp5);

  int gRow = (N + 63) / 64;
  // L1: MFMA GEMM(128->64)*dinv, AGG(64)+BN+ReLU emit *dinv for L2's agg
  k_mgemm<128, 64, 0, true><<<gRow, TPB, 0, stream>>>(x, wp1, dinv, nullptr, nullptr, nullptr, nullptr, nullptr, bufB, N);
  k_agg<64, 2, __half><<<(N + 31) / 32, TPB, 0, stream>>>(bufB, rowptr, colidx, order, dinv, b1, g1, be1, m1, v1, bufA, N);
  // L2: AGG(64) first, then MFMA GEMM(64->128)+bias+BN+ReLU
  k_agg<64, 3, __half><<<(N + 31) / 32, TPB, 0, stream>>>(bufA, rowptr, colidx, order, dinv, nullptr, nullptr, nullptr, nullptr, nullptr, bufB, N);
  k_mgemm<64, 128, 1, false><<<gRow, TPB, 0, stream>>>(bufB, wp2, nullptr, b2, g2, be2, m2, v2, bufA, N);
  // L3
  k_mgemm<128, 64, 0, false><<<gRow, TPB, 0, stream>>>(bufA, wp3, dinv, nullptr, nullptr, nullptr, nullptr, nullptr, bufB, N);
  k_agg<64, 1, __half><<<(N + 31) / 32, TPB, 0, stream>>>(bufB, rowptr, colidx, order, dinv, b3, g3, be3, m3, v3, bufA, N);
  // L4
  k_mgemm<64, 32, 0, false><<<gRow, TPB, 0, stream>>>(bufA, wp4, dinv, nullptr, nullptr, nullptr, nullptr, nullptr, bufB, N);
  k_agg<32, 1, __half><<<(N + 63) / 64, TPB, 0, stream>>>(bufB, rowptr, colidx, order, dinv, b4, g4, be4, m4, v4, bufA, N);
  // L5 -> f32 out
  k_mgemm<32, 16, 0, false><<<gRow, TPB, 0, stream>>>(bufA, wp5, dinv, nullptr, nullptr, nullptr, nullptr, nullptr, bufB, N);
  k_agg<16, 0, float><<<(N + 127) / 128, TPB, 0, stream>>>(bufB, rowptr, colidx, order, dinv, b5, nullptr, nullptr, nullptr, nullptr, out, N);
}

// Round 6
// 417.197 us; speedup vs baseline: 2.1864x; 2.1864x over previous
//
#include <hip/hip_runtime.h>
#include <hip/hip_fp16.h>

#define BEPS 1e-5f
static constexpr int TPB = 256;
static constexpr int G_SC = 512;      // scatter workgroups
static constexpr int BK_SHIFT = 8;    // bucket = 256-node range
static constexpr int BK_NODES = 256;
static constexpr int KMAX = 512;      // max buckets (N <= 131072)

union F4H8 { float4 f4; __half2 h2[4]; };  // 16B = 8 halfs

typedef _Float16 half8 __attribute__((ext_vector_type(8)));
typedef float floatx4 __attribute__((ext_vector_type(4)));

// ================= CSR build: two-level bucket counting sort =================

__global__ __launch_bounds__(TPB) void k_zero_int(int* __restrict__ p, int n) {
  int i = blockIdx.x * TPB + threadIdx.x;
  if (i < n) p[i] = 0;
}

__global__ __launch_bounds__(TPB) void k_hist(const int* __restrict__ dst,
                                              int* __restrict__ histG,
                                              int* __restrict__ btot,
                                              int E, int K, int chunk) {
  __shared__ int lh[KMAX];
  int g = blockIdx.x, t = threadIdx.x;
  for (int i = t; i < KMAX; i += TPB) lh[i] = 0;
  __syncthreads();
  int e0 = g * chunk, e1 = min(E, e0 + chunk);
  for (int e = e0 + t; e < e1; e += TPB) atomicAdd(&lh[dst[e] >> BK_SHIFT], 1);
  __syncthreads();
  for (int i = t; i < K; i += TPB) {
    histG[i * G_SC + g] = lh[i];
    atomicAdd(&btot[i], lh[i]);
  }
}

__global__ __launch_bounds__(KMAX) void k_bbase(const int* __restrict__ btot,
                                                int* __restrict__ bbase, int K) {
  __shared__ int sh[KMAX];
  int t = threadIdx.x;
  int v = (t < K) ? btot[t] : 0;
  sh[t] = v;
  __syncthreads();
  for (int s = 1; s < KMAX; s <<= 1) {
    int x = sh[t];
    int y = (t >= s) ? sh[t - s] : 0;
    __syncthreads();
    sh[t] = x + y;
    __syncthreads();
  }
  if (t < K) bbase[t] = sh[t] - v;
  if (t == 0) bbase[K] = sh[K - 1];
}

__global__ __launch_bounds__(G_SC) void k_offs(const int* __restrict__ histG,
                                               const int* __restrict__ bbase,
                                               int* __restrict__ offs) {
  __shared__ int sh[G_SC];
  int b = blockIdx.x, t = threadIdx.x;
  int v = histG[b * G_SC + t];
  sh[t] = v;
  __syncthreads();
  for (int s = 1; s < G_SC; s <<= 1) {
    int x = sh[t];
    int y = (t >= s) ? sh[t - s] : 0;
    __syncthreads();
    sh[t] = x + y;
    __syncthreads();
  }
  offs[b * G_SC + t] = bbase[b] + sh[t] - v;
}

__global__ __launch_bounds__(TPB) void k_scatter(const int* __restrict__ src,
                                                 const int* __restrict__ dst,
                                                 const int* __restrict__ offs,
                                                 unsigned int* __restrict__ pairs,
                                                 int E, int K, int chunk) {
  __shared__ int cur[KMAX];
  int g = blockIdx.x, t = threadIdx.x;
  for (int i = t; i < K; i += TPB) cur[i] = offs[i * G_SC + g];
  __syncthreads();
  int e0 = g * chunk, e1 = min(E, e0 + chunk);
  for (int e = e0 + t; e < e1; e += TPB) {
    int d = dst[e];
    int b = d >> BK_SHIFT;
    int pos = atomicAdd(&cur[b], 1);
    pairs[pos] = (unsigned int)src[e] | ((unsigned int)(d & (BK_NODES - 1)) << 20);
  }
}

// per-bucket LDS counting sort -> colidx, rowptr, dinv, and bucket-local
// degree-sorted order[] (descending). NO global atomics (R5 post-mortem:
// 100k atomics onto 64 global counters serialized at ~2.7ns each = 270us;
// same again in k_degscatter. All ordering work now stays in LDS.)
__global__ __launch_bounds__(TPB) void k_bucket_sort(const unsigned int* __restrict__ pairs,
                                                     const int* __restrict__ bbase,
                                                     int* __restrict__ rowptr,
                                                     int* __restrict__ colidx,
                                                     float* __restrict__ dinv,
                                                     int* __restrict__ order,
                                                     int N, int E) {
  __shared__ int deg[BK_NODES];
  __shared__ int sh[BK_NODES];
  __shared__ int dcur[64];
  int b = blockIdx.x, t = threadIdx.x;
  int base = bbase[b], end = bbase[b + 1];
  int n0 = b << BK_SHIFT;
  int nNodes = min(BK_NODES, N - n0);
  deg[t] = 0;
  if (t < 64) dcur[t] = 0;
  __syncthreads();
  for (int e = base + t; e < end; e += TPB) atomicAdd(&deg[pairs[e] >> 20], 1);
  __syncthreads();
  int v = deg[t];
  int dbin = min(v, 63);
  sh[t] = v;
  if (t < nNodes) atomicAdd(&dcur[dbin], 1);  // LDS degree histogram
  __syncthreads();
  for (int s = 1; s < TPB; s <<= 1) {
    int x = sh[t];
    int y = (t >= s) ? sh[t - s] : 0;
    __syncthreads();
    sh[t] = x + y;
    __syncthreads();
  }
  int excl = sh[t] - v;
  if (t < nNodes) {
    rowptr[n0 + t] = base + excl;
    dinv[n0 + t] = rsqrtf((float)(v + 1));
  }
  if (b == (int)gridDim.x - 1 && t == 0) rowptr[N] = E;
  __syncthreads();
  if (t == 0) {  // suffix-exclusive scan: descending-degree bases (64 bins, serial ok)
    int accum = 0;
    for (int d = 63; d >= 0; --d) { int c = dcur[d]; dcur[d] = accum; accum += c; }
  }
  __syncthreads();
  if (t < nNodes) {
    int pos = atomicAdd(&dcur[dbin], 1);  // LDS cursor
    order[n0 + pos] = n0 + t;             // bucket-local degree-sorted order
  }
  __syncthreads();
  deg[t] = excl;  // reuse as colidx cursor
  __syncthreads();
  for (int e = base + t; e < end; e += TPB) {
    unsigned int p = pairs[e];
    int pos = atomicAdd(&deg[p >> 20], 1);
    colidx[base + pos] = (int)(p & 0xFFFFFu);
  }
}

// ================= W pack (all 5 weights, one launch) =================
__device__ inline void packone(const float* __restrict__ W, _Float16* __restrict__ Wp,
                               int i, int FO) {
  int j = i & 7, lane = (i >> 3) & 63, tile = i >> 9;
  int nct = FO >> 4, ct = tile % nct, kch = tile / nct;
  int k = kch * 32 + ((lane >> 4) << 3) + j;
  int n = (ct << 4) + (lane & 15);
  Wp[i] = (_Float16)W[k * FO + n];
}

__global__ __launch_bounds__(TPB) void k_packAll(const float* w1, _Float16* p1,
                                                 const float* w2, _Float16* p2,
                                                 const float* w3, _Float16* p3,
                                                 const float* w4, _Float16* p4,
                                                 const float* w5, _Float16* p5) {
  int i = blockIdx.x * TPB + threadIdx.x;
  if (i < 8192) packone(w1, p1, i, 64);
  else if (i < 16384) packone(w2, p2, i - 8192, 128);
  else if (i < 24576) packone(w3, p3, i - 16384, 64);
  else if (i < 26624) packone(w4, p4, i - 24576, 32);
  else if (i < 27136) packone(w5, p5, i - 26624, 16);
}

// ================= MFMA GEMM =================
// Block = 4 waves; wave computes 16 rows x FO via v_mfma_f32_16x16x32_f16.
// EPI 0: out = acc*dinv[row] (fp16)   EPI 1: out = relu(bn(acc+bias)) (fp16)
template <int FI, int FO, int EPI, bool F32IN>
__global__ __launch_bounds__(TPB) void k_mgemm(const void* __restrict__ hin,
                                               const _Float16* __restrict__ Wp,
                                               const float* __restrict__ dinv,
                                               const float* __restrict__ bias,
                                               const float* __restrict__ g,
                                               const float* __restrict__ be,
                                               const float* __restrict__ m,
                                               const float* __restrict__ v,
                                               __half* __restrict__ out, int N) {
  constexpr int NCT = FO / 16;
  constexpr int NKC = FI / 32;
  __shared__ float4 Wsh[NKC * NCT * 64];
  for (int i = threadIdx.x; i < NKC * NCT * 64; i += TPB)
    Wsh[i] = reinterpret_cast<const float4*>(Wp)[i];
  __syncthreads();

  int lane = threadIdx.x & 63;
  int wv = threadIdx.x >> 6;
  int quad = lane >> 4;
  int rowBase = blockIdx.x * 64 + wv * 16;
  int rA = min(rowBase + (lane & 15), N - 1);

  floatx4 acc[NCT];
#pragma unroll
  for (int ct = 0; ct < NCT; ++ct) acc[ct] = (floatx4){0.f, 0.f, 0.f, 0.f};

#pragma unroll
  for (int kch = 0; kch < NKC; ++kch) {
    half8 a;
    if constexpr (F32IN) {
      const float4* xp = reinterpret_cast<const float4*>(hin);
      size_t idx = ((size_t)rA * FI + kch * 32 + quad * 8) >> 2;
      float4 fa = xp[idx], fb = xp[idx + 1];
      a[0] = (_Float16)fa.x; a[1] = (_Float16)fa.y; a[2] = (_Float16)fa.z; a[3] = (_Float16)fa.w;
      a[4] = (_Float16)fb.x; a[5] = (_Float16)fb.y; a[6] = (_Float16)fb.z; a[7] = (_Float16)fb.w;
    } else {
      union { float4 f4; half8 h8; } ua;
      ua.f4 = reinterpret_cast<const float4*>(hin)[((size_t)rA * FI + kch * 32 + quad * 8) >> 3];
      a = ua.h8;
    }
#pragma unroll
    for (int ct = 0; ct < NCT; ++ct) {
      union { float4 f4; half8 h8; } ub;
      ub.f4 = Wsh[(kch * NCT + ct) * 64 + lane];
      acc[ct] = __builtin_amdgcn_mfma_f32_16x16x32_f16(a, ub.h8, acc[ct], 0, 0, 0);
    }
  }

  int r0 = rowBase + quad * 4;
  if (EPI == 0) {
    float dv[4];
#pragma unroll
    for (int reg = 0; reg < 4; ++reg) dv[reg] = (r0 + reg < N) ? dinv[r0 + reg] : 0.f;
#pragma unroll
    for (int ct = 0; ct < NCT; ++ct) {
      int col = ct * 16 + (lane & 15);
#pragma unroll
      for (int reg = 0; reg < 4; ++reg) {
        int r = r0 + reg;
        if (r < N) out[(size_t)r * FO + col] = __float2half(acc[ct][reg] * dv[reg]);
      }
    }
  } else {
#pragma unroll
    for (int ct = 0; ct < NCT; ++ct) {
      int col = ct * 16 + (lane & 15);
      float sc = g[col] * rsqrtf(v[col] + BEPS);
      float bb = bias[col] - m[col];
      float ee = be[col];
#pragma unroll
      for (int reg = 0; reg < 4; ++reg) {
        int r = r0 + reg;
        if (r < N) out[(size_t)r * FO + col] = __float2half(fmaxf((acc[ct][reg] + bb) * sc + ee, 0.f));
      }
    }
  }
}

// ================= Aggregation (fp16 in, f32 accumulate) =================
// Processes nodes via bucket-local degree-sorted order[] (a wave's nodes have
// near-equal degree -> minimal lockstep divergence). Edge loop unrolled 8x.
// MODE 0: val+bias (TO=float, final)  MODE 1: relu(bn(val+bias))
// MODE 2: relu(bn(val+bias))*dinv     MODE 3: val (pre-GEMM agg)
template <int F, int MODE, typename TO>
__global__ __launch_bounds__(TPB) void k_agg(const __half* __restrict__ in,
                                             const int* __restrict__ rowptr,
                                             const int* __restrict__ colidx,
                                             const int* __restrict__ order,
                                             const float* __restrict__ dinv,
                                             const float* __restrict__ bias,
                                             const float* __restrict__ g,
                                             const float* __restrict__ be,
                                             const float* __restrict__ m,
                                             const float* __restrict__ v,
                                             TO* __restrict__ out, int N) {
  constexpr int V = F / 8;
  constexpr int NPB = TPB / V;
  int gidx = blockIdx.x * NPB + (int)(threadIdx.x / V);
  int lane = threadIdx.x % V;
  if (gidx >= N) return;
  int node = order[gidx];
  const float4* in16 = reinterpret_cast<const float4*>(in);
  const size_t rs = F / 8;
  float acc[8];
  {
    F4H8 u;
    u.f4 = in16[(size_t)node * rs + lane];
#pragma unroll
    for (int i = 0; i < 4; ++i) {
      float2 t2 = __half22float2(u.h2[i]);
      acc[2 * i] = t2.x;
      acc[2 * i + 1] = t2.y;
    }
  }
  int e0 = rowptr[node], e1 = rowptr[node + 1];
  int e = e0;
  for (; e + 8 <= e1; e += 8) {
    int s[8];
#pragma unroll
    for (int q = 0; q < 8; ++q) s[q] = colidx[e + q];
    F4H8 u[8];
#pragma unroll
    for (int q = 0; q < 8; ++q) u[q].f4 = in16[(size_t)s[q] * rs + lane];
#pragma unroll
    for (int q = 0; q < 8; ++q) {
#pragma unroll
      for (int i = 0; i < 4; ++i) {
        float2 t2 = __half22float2(u[q].h2[i]);
        acc[2 * i] += t2.x;
        acc[2 * i + 1] += t2.y;
      }
    }
  }
  for (; e + 4 <= e1; e += 4) {
    int s0 = colidx[e + 0], s1 = colidx[e + 1], s2 = colidx[e + 2], s3 = colidx[e + 3];
    F4H8 u0, u1, u2, u3;
    u0.f4 = in16[(size_t)s0 * rs + lane];
    u1.f4 = in16[(size_t)s1 * rs + lane];
    u2.f4 = in16[(size_t)s2 * rs + lane];
    u3.f4 = in16[(size_t)s3 * rs + lane];
#pragma unroll
    for (int i = 0; i < 4; ++i) {
      float2 a = __half22float2(u0.h2[i]), b = __half22float2(u1.h2[i]);
      float2 c = __half22float2(u2.h2[i]), d = __half22float2(u3.h2[i]);
      acc[2 * i] += (a.x + b.x) + (c.x + d.x);
      acc[2 * i + 1] += (a.y + b.y) + (c.y + d.y);
    }
  }
  for (; e < e1; ++e) {
    F4H8 u;
    u.f4 = in16[(size_t)colidx[e] * rs + lane];
#pragma unroll
    for (int i = 0; i < 4; ++i) {
      float2 t2 = __half22float2(u.h2[i]);
      acc[2 * i] += t2.x;
      acc[2 * i + 1] += t2.y;
    }
  }
  float dv = dinv[node];
#pragma unroll
  for (int i = 0; i < 8; ++i) acc[i] *= dv;
  if (MODE == 0) {
    float4 ba = reinterpret_cast<const float4*>(bias)[lane * 2];
    float4 bb = reinterpret_cast<const float4*>(bias)[lane * 2 + 1];
    acc[0] += ba.x; acc[1] += ba.y; acc[2] += ba.z; acc[3] += ba.w;
    acc[4] += bb.x; acc[5] += bb.y; acc[6] += bb.z; acc[7] += bb.w;
  } else if (MODE == 1 || MODE == 2) {
    const float4* B = reinterpret_cast<const float4*>(bias);
    const float4* G = reinterpret_cast<const float4*>(g);
    const float4* Be = reinterpret_cast<const float4*>(be);
    const float4* M = reinterpret_cast<const float4*>(m);
    const float4* Vv = reinterpret_cast<const float4*>(v);
#pragma unroll
    for (int h = 0; h < 2; ++h) {
      float4 b4 = B[lane * 2 + h], g4 = G[lane * 2 + h], e4 = Be[lane * 2 + h];
      float4 m4 = M[lane * 2 + h], v4 = Vv[lane * 2 + h];
      float* a = acc + 4 * h;
      a[0] = fmaxf((a[0] + b4.x - m4.x) * (g4.x * rsqrtf(v4.x + BEPS)) + e4.x, 0.f);
      a[1] = fmaxf((a[1] + b4.y - m4.y) * (g4.y * rsqrtf(v4.y + BEPS)) + e4.y, 0.f);
      a[2] = fmaxf((a[2] + b4.z - m4.z) * (g4.z * rsqrtf(v4.z + BEPS)) + e4.z, 0.f);
      a[3] = fmaxf((a[3] + b4.w - m4.w) * (g4.w * rsqrtf(v4.w + BEPS)) + e4.w, 0.f);
    }
    if (MODE == 2) {
#pragma unroll
      for (int i = 0; i < 8; ++i) acc[i] *= dv;
    }
  }
  if constexpr (sizeof(TO) == 2) {
    F4H8 u;
#pragma unroll
    for (int i = 0; i < 4; ++i) u.h2[i] = __floats2half2_rn(acc[2 * i], acc[2 * i + 1]);
    reinterpret_cast<float4*>(out)[(size_t)node * rs + lane] = u.f4;
  } else {
    float4 o0 = {acc[0], acc[1], acc[2], acc[3]};
    float4 o1 = {acc[4], acc[5], acc[6], acc[7]};
    float4* op = reinterpret_cast<float4*>((float*)out + (size_t)node * F + lane * 8);
    op[0] = o0;
    op[1] = o1;
  }
}

// ================= launch =================

extern "C" void kernel_launch(void* const* d_in, const int* in_sizes, int n_in,
                              void* d_out, int out_size, void* d_ws, size_t ws_size,
                              hipStream_t stream) {
  const float* x = (const float*)d_in[0];
  const int* ei = (const int*)d_in[1];
  const int N = in_sizes[0] / 128;
  const int E = in_sizes[1] / 2;
  const int* src = ei;
  const int* dst = ei + E;

  const float* w1 = (const float*)d_in[2];  const float* b1 = (const float*)d_in[3];
  const float* w2 = (const float*)d_in[4];  const float* b2 = (const float*)d_in[5];
  const float* w3 = (const float*)d_in[6];  const float* b3 = (const float*)d_in[7];
  const float* w4 = (const float*)d_in[8];  const float* b4 = (const float*)d_in[9];
  const float* w5 = (const float*)d_in[10]; const float* b5 = (const float*)d_in[11];
  const float* g1 = (const float*)d_in[12]; const float* be1 = (const float*)d_in[13];
  const float* m1 = (const float*)d_in[14]; const float* v1 = (const float*)d_in[15];
  const float* g2 = (const float*)d_in[16]; const float* be2 = (const float*)d_in[17];
  const float* m2 = (const float*)d_in[18]; const float* v2 = (const float*)d_in[19];
  const float* g3 = (const float*)d_in[20]; const float* be3 = (const float*)d_in[21];
  const float* m3 = (const float*)d_in[22]; const float* v3 = (const float*)d_in[23];
  const float* g4 = (const float*)d_in[24]; const float* be4 = (const float*)d_in[25];
  const float* m4 = (const float*)d_in[26]; const float* v4 = (const float*)d_in[27];
  float* out = (float*)d_out;

  char* ws = (char*)d_ws;
  size_t off = 0;
  auto alloc = [&](size_t bytes) -> void* {
    void* p = ws + off;
    off += (bytes + 255) & ~(size_t)255;
    return p;
  };
  float*        dinv   = (float*)alloc((size_t)N * 4);
  int*          rowptr = (int*)alloc((size_t)(N + 1) * 4);
  int*          colidx = (int*)alloc((size_t)E * 4);
  unsigned int* pairs  = (unsigned int*)alloc((size_t)E * 4);
  int*          histG  = (int*)alloc((size_t)KMAX * G_SC * 4);
  int*          offs   = (int*)alloc((size_t)KMAX * G_SC * 4);
  int*          btot   = (int*)alloc(KMAX * 4);
  int*          order  = (int*)alloc((size_t)N * 4);
  int*          bbase  = (int*)alloc((KMAX + 1) * 4);
  _Float16*     wp1    = (_Float16*)alloc(128 * 64 * 2);
  _Float16*     wp2    = (_Float16*)alloc(64 * 128 * 2);
  _Float16*     wp3    = (_Float16*)alloc(128 * 64 * 2);
  _Float16*     wp4    = (_Float16*)alloc(64 * 32 * 2);
  _Float16*     wp5    = (_Float16*)alloc(32 * 16 * 2);
  __half*       bufA   = (__half*)alloc((size_t)N * 128 * 2);
  __half*       bufB   = (__half*)alloc((size_t)N * 128 * 2);
  (void)ws_size; (void)n_in; (void)out_size;

  const int K = (N + BK_NODES - 1) >> BK_SHIFT;  // 391 for N=100000
  const int chunk = (E + G_SC - 1) / G_SC;

  // CSR build (order[] built inside k_bucket_sort, LDS-only sorting)
  k_zero_int<<<2, TPB, 0, stream>>>(btot, KMAX);
  k_hist<<<G_SC, TPB, 0, stream>>>(dst, histG, btot, E, K, chunk);
  k_bbase<<<1, KMAX, 0, stream>>>(btot, bbase, K);
  k_offs<<<K, G_SC, 0, stream>>>(histG, bbase, offs);
  k_scatter<<<G_SC, TPB, 0, stream>>>(src, dst, offs, pairs, E, K, chunk);
  k_bucket_sort<<<K, TPB, 0, stream>>>(pairs, bbase, rowptr, colidx, dinv, order, N, E);

  // pack all weights into MFMA B-fragment layout (one launch)
  k_packAll<<<(27136 + TPB - 1) / TPB, TPB, 0, stream>>>(w1, wp1, w2, wp2, w3, wp3, w4, wp4, w5, wp5);

  int gRow = (N + 63) / 64;
  // L1: MFMA GEMM(128->64)*dinv, AGG(64)+BN+ReLU emit *dinv for L2's agg
  k_mgemm<128, 64, 0, true><<<gRow, TPB, 0, stream>>>(x, wp1, dinv, nullptr, nullptr, nullptr, nullptr, nullptr, bufB, N);
  k_agg<64, 2, __half><<<(N + 31) / 32, TPB, 0, stream>>>(bufB, rowptr, colidx, order, dinv, b1, g1, be1, m1, v1, bufA, N);
  // L2: AGG(64) first, then MFMA GEMM(64->128)+bias+BN+ReLU
  k_agg<64, 3, __half><<<(N + 31) / 32, TPB, 0, stream>>>(bufA, rowptr, colidx, order, dinv, nullptr, nullptr, nullptr, nullptr, nullptr, bufB, N);
  k_mgemm<64, 128, 1, false><<<gRow, TPB, 0, stream>>>(bufB, wp2, nullptr, b2, g2, be2, m2, v2, bufA, N);
  // L3
  k_mgemm<128, 64, 0, false><<<gRow, TPB, 0, stream>>>(bufA, wp3, dinv, nullptr, nullptr, nullptr, nullptr, nullptr, bufB, N);
  k_agg<64, 1, __half><<<(N + 31) / 32, TPB, 0, stream>>>(bufB, rowptr, colidx, order, dinv, b3, g3, be3, m3, v3, bufA, N);
  // L4
  k_mgemm<64, 32, 0, false><<<gRow, TPB, 0, stream>>>(bufA, wp4, dinv, nullptr, nullptr, nullptr, nullptr, nullptr, bufB, N);
  k_agg<32, 1, __half><<<(N + 63) / 64, TPB, 0, stream>>>(bufB, rowptr, colidx, order, dinv, b4, g4, be4, m4, v4, bufA, N);
  // L5 -> f32 out
  k_mgemm<32, 16, 0, false><<<gRow, TPB, 0, stream>>>(bufA, wp5, dinv, nullptr, nullptr, nullptr, nullptr, nullptr, bufB, N);
  k_agg<16, 0, float><<<(N + 127) / 128, TPB, 0, stream>>>(bufB, rowptr, colidx, order, dinv, b5, nullptr, nullptr, nullptr, nullptr, out, N);
}

// Round 7
// 363.822 us; speedup vs baseline: 2.5072x; 1.1467x over previous
//
#include <hip/hip_runtime.h>
#include <hip/hip_fp16.h>

#define BEPS 1e-5f
static constexpr int TPB = 256;
static constexpr int G_SC = 512;      // scatter workgroups
static constexpr int BK_SHIFT = 8;    // bucket = 256-node range
static constexpr int BK_NODES = 256;
static constexpr int KMAX = 512;      // max buckets (N <= 131072)
static constexpr int BK_SLACK = 2048; // per-bucket colidx padding slack (>= 256*7 + 8)

union F4H8 { float4 f4; __half2 h2[4]; };  // 16B = 8 halfs

typedef _Float16 half8 __attribute__((ext_vector_type(8)));
typedef float floatx4 __attribute__((ext_vector_type(4)));

// ================= CSR build: two-level bucket counting sort =================

__global__ __launch_bounds__(TPB) void k_zero_int(int* __restrict__ p, int n) {
  int i = blockIdx.x * TPB + threadIdx.x;
  if (i < n) p[i] = 0;
}

__global__ __launch_bounds__(TPB) void k_hist(const int* __restrict__ dst,
                                              int* __restrict__ histG,
                                              int* __restrict__ btot,
                                              int E, int K, int chunk) {
  __shared__ int lh[KMAX];
  int g = blockIdx.x, t = threadIdx.x;
  for (int i = t; i < KMAX; i += TPB) lh[i] = 0;
  __syncthreads();
  int e0 = g * chunk, e1 = min(E, e0 + chunk);
  for (int e = e0 + t; e < e1; e += TPB) atomicAdd(&lh[dst[e] >> BK_SHIFT], 1);
  __syncthreads();
  for (int i = t; i < K; i += TPB) {
    histG[i * G_SC + g] = lh[i];
    atomicAdd(&btot[i], lh[i]);
  }
}

__global__ __launch_bounds__(KMAX) void k_bbase(const int* __restrict__ btot,
                                                int* __restrict__ bbase, int K) {
  __shared__ int sh[KMAX];
  int t = threadIdx.x;
  int v = (t < K) ? btot[t] : 0;
  sh[t] = v;
  __syncthreads();
  for (int s = 1; s < KMAX; s <<= 1) {
    int x = sh[t];
    int y = (t >= s) ? sh[t - s] : 0;
    __syncthreads();
    sh[t] = x + y;
    __syncthreads();
  }
  if (t < K) bbase[t] = sh[t] - v;
  if (t == 0) bbase[K] = sh[K - 1];
}

__global__ __launch_bounds__(G_SC) void k_offs(const int* __restrict__ histG,
                                               const int* __restrict__ bbase,
                                               int* __restrict__ offs) {
  __shared__ int sh[G_SC];
  int b = blockIdx.x, t = threadIdx.x;
  int v = histG[b * G_SC + t];
  sh[t] = v;
  __syncthreads();
  for (int s = 1; s < G_SC; s <<= 1) {
    int x = sh[t];
    int y = (t >= s) ? sh[t - s] : 0;
    __syncthreads();
    sh[t] = x + y;
    __syncthreads();
  }
  offs[b * G_SC + t] = bbase[b] + sh[t] - v;
}

__global__ __launch_bounds__(TPB) void k_scatter(const int* __restrict__ src,
                                                 const int* __restrict__ dst,
                                                 const int* __restrict__ offs,
                                                 unsigned int* __restrict__ pairs,
                                                 int E, int K, int chunk) {
  __shared__ int cur[KMAX];
  int g = blockIdx.x, t = threadIdx.x;
  for (int i = t; i < K; i += TPB) cur[i] = offs[i * G_SC + g];
  __syncthreads();
  int e0 = g * chunk, e1 = min(E, e0 + chunk);
  for (int e = e0 + t; e < e1; e += TPB) {
    int d = dst[e];
    int b = d >> BK_SHIFT;
    int pos = atomicAdd(&cur[b], 1);
    pairs[pos] = (unsigned int)src[e] | ((unsigned int)(d & (BK_NODES - 1)) << 20);
  }
}

// per-bucket LDS counting sort -> PADDED colidx (each node's list padded to a
// multiple of 8 with sentinel N -> zero row; 8-aligned starts enable aligned
// int4 index loads and tail-free agg loops). rowptr = padded start,
// rowend = padded end. Bucket b's colidx region starts at
// align8(bbase[b] + b*BK_SLACK); slack between buckets is never referenced.
__global__ __launch_bounds__(TPB) void k_bucket_sort(const unsigned int* __restrict__ pairs,
                                                     const int* __restrict__ bbase,
                                                     int* __restrict__ rowptr,
                                                     int* __restrict__ rowend,
                                                     int* __restrict__ colidx,
                                                     float* __restrict__ dinv,
                                                     int N, int E) {
  __shared__ int cur[BK_NODES];
  __shared__ int sh[BK_NODES];
  int b = blockIdx.x, t = threadIdx.x;
  int base = bbase[b], end = bbase[b + 1];
  int n0 = b << BK_SHIFT;
  int nNodes = min(BK_NODES, N - n0);
  cur[t] = 0;
  __syncthreads();
  for (int e = base + t; e < end; e += TPB) atomicAdd(&cur[pairs[e] >> 20], 1);
  __syncthreads();
  int v = cur[t];                 // raw degree
  int pd = (v + 7) & ~7;          // padded degree
  sh[t] = pd;
  __syncthreads();
  for (int s = 1; s < TPB; s <<= 1) {
    int x = sh[t];
    int y = (t >= s) ? sh[t - s] : 0;
    __syncthreads();
    sh[t] = x + y;
    __syncthreads();
  }
  int Bb = (base + b * BK_SLACK + 7) & ~7;   // padded bucket base (8-aligned)
  int start = Bb + (sh[t] - pd);             // 8-aligned per-node start
  if (t < nNodes) {
    rowptr[n0 + t] = start;
    rowend[n0 + t] = start + pd;
    dinv[n0 + t] = rsqrtf((float)(v + 1));
    for (int i = start + v; i < start + pd; ++i) colidx[i] = N;  // pads -> zero row
  }
  __syncthreads();
  cur[t] = start;  // absolute scatter cursor
  __syncthreads();
  for (int e = base + t; e < end; e += TPB) {
    unsigned int p = pairs[e];
    int pos = atomicAdd(&cur[p >> 20], 1);
    colidx[pos] = (int)(p & 0xFFFFFu);
  }
}

// ================= W pack (all 5 weights) + bufA zero-row init =================
__device__ inline void packone(const float* __restrict__ W, _Float16* __restrict__ Wp,
                               int i, int FO) {
  int j = i & 7, lane = (i >> 3) & 63, tile = i >> 9;
  int nct = FO >> 4, ct = tile % nct, kch = tile / nct;
  int k = kch * 32 + ((lane >> 4) << 3) + j;
  int n = (ct << 4) + (lane & 15);
  Wp[i] = (_Float16)W[k * FO + n];
}

__global__ __launch_bounds__(TPB) void k_packAll(const float* w1, _Float16* p1,
                                                 const float* w2, _Float16* p2,
                                                 const float* w3, _Float16* p3,
                                                 const float* w4, _Float16* p4,
                                                 const float* w5, _Float16* p5,
                                                 __half* bufA, int N) {
  int i = blockIdx.x * TPB + threadIdx.x;
  if (i < 8192) packone(w1, p1, i, 64);
  else if (i < 16384) packone(w2, p2, i - 8192, 128);
  else if (i < 24576) packone(w3, p3, i - 16384, 64);
  else if (i < 26624) packone(w4, p4, i - 24576, 32);
  else if (i < 27136) packone(w5, p5, i - 26624, 16);
  else if (i < 27144) {  // zero bufA's F=64 pad row N (for agg2's gathers)
    float4 z = {0.f, 0.f, 0.f, 0.f};
    reinterpret_cast<float4*>(bufA + (size_t)64 * N)[i - 27136] = z;
  }
}

// ================= MFMA GEMM =================
// Block = 4 waves; wave computes 16 rows x FO via v_mfma_f32_16x16x32_f16.
// Rows >= N are written as ZERO (EPI 0) so the padded-CSR sentinel row N of
// the output buffer is always a zero row for the following agg's gathers.
template <int FI, int FO, int EPI, bool F32IN>
__global__ __launch_bounds__(TPB) void k_mgemm(const void* __restrict__ hin,
                                               const _Float16* __restrict__ Wp,
                                               const float* __restrict__ dinv,
                                               const float* __restrict__ bias,
                                               const float* __restrict__ g,
                                               const float* __restrict__ be,
                                               const float* __restrict__ m,
                                               const float* __restrict__ v,
                                               __half* __restrict__ out, int N) {
  constexpr int NCT = FO / 16;
  constexpr int NKC = FI / 32;
  __shared__ float4 Wsh[NKC * NCT * 64];
  for (int i = threadIdx.x; i < NKC * NCT * 64; i += TPB)
    Wsh[i] = reinterpret_cast<const float4*>(Wp)[i];
  __syncthreads();

  int lane = threadIdx.x & 63;
  int wv = threadIdx.x >> 6;
  int quad = lane >> 4;
  int rowBase = blockIdx.x * 64 + wv * 16;
  int rA = min(rowBase + (lane & 15), N - 1);

  floatx4 acc[NCT];
#pragma unroll
  for (int ct = 0; ct < NCT; ++ct) acc[ct] = (floatx4){0.f, 0.f, 0.f, 0.f};

#pragma unroll
  for (int kch = 0; kch < NKC; ++kch) {
    half8 a;
    if constexpr (F32IN) {
      const float4* xp = reinterpret_cast<const float4*>(hin);
      size_t idx = ((size_t)rA * FI + kch * 32 + quad * 8) >> 2;
      float4 fa = xp[idx], fb = xp[idx + 1];
      a[0] = (_Float16)fa.x; a[1] = (_Float16)fa.y; a[2] = (_Float16)fa.z; a[3] = (_Float16)fa.w;
      a[4] = (_Float16)fb.x; a[5] = (_Float16)fb.y; a[6] = (_Float16)fb.z; a[7] = (_Float16)fb.w;
    } else {
      union { float4 f4; half8 h8; } ua;
      ua.f4 = reinterpret_cast<const float4*>(hin)[((size_t)rA * FI + kch * 32 + quad * 8) >> 3];
      a = ua.h8;
    }
#pragma unroll
    for (int ct = 0; ct < NCT; ++ct) {
      union { float4 f4; half8 h8; } ub;
      ub.f4 = Wsh[(kch * NCT + ct) * 64 + lane];
      acc[ct] = __builtin_amdgcn_mfma_f32_16x16x32_f16(a, ub.h8, acc[ct], 0, 0, 0);
    }
  }

  int r0 = rowBase + quad * 4;
  if (EPI == 0) {
    float dv[4];
#pragma unroll
    for (int reg = 0; reg < 4; ++reg) dv[reg] = (r0 + reg < N) ? dinv[r0 + reg] : 0.f;  // rows>=N -> 0
#pragma unroll
    for (int ct = 0; ct < NCT; ++ct) {
      int col = ct * 16 + (lane & 15);
#pragma unroll
      for (int reg = 0; reg < 4; ++reg) {
        int r = r0 + reg;
        out[(size_t)r * FO + col] = __float2half(acc[ct][reg] * dv[reg]);
      }
    }
  } else {
#pragma unroll
    for (int ct = 0; ct < NCT; ++ct) {
      int col = ct * 16 + (lane & 15);
      float sc = g[col] * rsqrtf(v[col] + BEPS);
      float bb = bias[col] - m[col];
      float ee = be[col];
#pragma unroll
      for (int reg = 0; reg < 4; ++reg) {
        int r = r0 + reg;
        out[(size_t)r * FO + col] = __float2half(fmaxf((acc[ct][reg] + bb) * sc + ee, 0.f));
      }
    }
  }
}

// ================= Aggregation (fp16 in, f32 accumulate) =================
// Padded CSR: [rowptr, rowend) is a multiple of 8, 8-aligned; pad entries
// gather the all-zero row N (L1-resident). Tail-free loop, aligned int4
// index loads, next-chunk indices software-pipelined over current gathers.
// MODE 0: val+bias (TO=float, final)  MODE 1: relu(bn(val+bias))
// MODE 2: relu(bn(val+bias))*dinv     MODE 3: val (pre-GEMM agg)
template <int F, int MODE, typename TO>
__global__ __launch_bounds__(TPB) void k_agg(const __half* __restrict__ in,
                                             const int* __restrict__ rowptr,
                                             const int* __restrict__ rowend,
                                             const int* __restrict__ colidx,
                                             const float* __restrict__ dinv,
                                             const float* __restrict__ bias,
                                             const float* __restrict__ g,
                                             const float* __restrict__ be,
                                             const float* __restrict__ m,
                                             const float* __restrict__ v,
                                             TO* __restrict__ out, int N) {
  constexpr int V = F / 8;
  constexpr int NPB = TPB / V;
  int node = blockIdx.x * NPB + (int)(threadIdx.x / V);
  int lane = threadIdx.x % V;
  if (node >= N) return;
  const float4* in16 = reinterpret_cast<const float4*>(in);
  const size_t rs = F / 8;
  float acc[8];
  {
    F4H8 u;
    u.f4 = in16[(size_t)node * rs + lane];
#pragma unroll
    for (int i = 0; i < 4; ++i) {
      float2 t2 = __half22float2(u.h2[i]);
      acc[2 * i] = t2.x;
      acc[2 * i + 1] = t2.y;
    }
  }
  int e0 = rowptr[node], e1 = rowend[node];
  int4 c0, c1;
  if (e0 < e1) {
    c0 = *reinterpret_cast<const int4*>(colidx + e0);
    c1 = *reinterpret_cast<const int4*>(colidx + e0 + 4);
  }
  for (int e = e0; e < e1; e += 8) {
    int4 n0, n1;
    int en = e + 8;
    if (en < e1) {  // prefetch next chunk's indices while gathers are in flight
      n0 = *reinterpret_cast<const int4*>(colidx + en);
      n1 = *reinterpret_cast<const int4*>(colidx + en + 4);
    }
    F4H8 u[8];
    u[0].f4 = in16[(size_t)c0.x * rs + lane];
    u[1].f4 = in16[(size_t)c0.y * rs + lane];
    u[2].f4 = in16[(size_t)c0.z * rs + lane];
    u[3].f4 = in16[(size_t)c0.w * rs + lane];
    u[4].f4 = in16[(size_t)c1.x * rs + lane];
    u[5].f4 = in16[(size_t)c1.y * rs + lane];
    u[6].f4 = in16[(size_t)c1.z * rs + lane];
    u[7].f4 = in16[(size_t)c1.w * rs + lane];
#pragma unroll
    for (int q = 0; q < 8; ++q) {
#pragma unroll
      for (int i = 0; i < 4; ++i) {
        float2 t2 = __half22float2(u[q].h2[i]);
        acc[2 * i] += t2.x;
        acc[2 * i + 1] += t2.y;
      }
    }
    c0 = n0; c1 = n1;
  }
  float dv = dinv[node];
#pragma unroll
  for (int i = 0; i < 8; ++i) acc[i] *= dv;
  if (MODE == 0) {
    float4 ba = reinterpret_cast<const float4*>(bias)[lane * 2];
    float4 bb = reinterpret_cast<const float4*>(bias)[lane * 2 + 1];
    acc[0] += ba.x; acc[1] += ba.y; acc[2] += ba.z; acc[3] += ba.w;
    acc[4] += bb.x; acc[5] += bb.y; acc[6] += bb.z; acc[7] += bb.w;
  } else if (MODE == 1 || MODE == 2) {
    const float4* B = reinterpret_cast<const float4*>(bias);
    const float4* G = reinterpret_cast<const float4*>(g);
    const float4* Be = reinterpret_cast<const float4*>(be);
    const float4* M = reinterpret_cast<const float4*>(m);
    const float4* Vv = reinterpret_cast<const float4*>(v);
#pragma unroll
    for (int h = 0; h < 2; ++h) {
      float4 b4 = B[lane * 2 + h], g4 = G[lane * 2 + h], e4 = Be[lane * 2 + h];
      float4 m4 = M[lane * 2 + h], v4 = Vv[lane * 2 + h];
      float* a = acc + 4 * h;
      a[0] = fmaxf((a[0] + b4.x - m4.x) * (g4.x * rsqrtf(v4.x + BEPS)) + e4.x, 0.f);
      a[1] = fmaxf((a[1] + b4.y - m4.y) * (g4.y * rsqrtf(v4.y + BEPS)) + e4.y, 0.f);
      a[2] = fmaxf((a[2] + b4.z - m4.z) * (g4.z * rsqrtf(v4.z + BEPS)) + e4.z, 0.f);
      a[3] = fmaxf((a[3] + b4.w - m4.w) * (g4.w * rsqrtf(v4.w + BEPS)) + e4.w, 0.f);
    }
    if (MODE == 2) {
#pragma unroll
      for (int i = 0; i < 8; ++i) acc[i] *= dv;
    }
  }
  if constexpr (sizeof(TO) == 2) {
    F4H8 u;
#pragma unroll
    for (int i = 0; i < 4; ++i) u.h2[i] = __floats2half2_rn(acc[2 * i], acc[2 * i + 1]);
    reinterpret_cast<float4*>(out)[(size_t)node * rs + lane] = u.f4;
  } else {
    float4 o0 = {acc[0], acc[1], acc[2], acc[3]};
    float4 o1 = {acc[4], acc[5], acc[6], acc[7]};
    float4* op = reinterpret_cast<float4*>((float*)out + (size_t)node * F + lane * 8);
    op[0] = o0;
    op[1] = o1;
  }
}

// ================= launch =================

extern "C" void kernel_launch(void* const* d_in, const int* in_sizes, int n_in,
                              void* d_out, int out_size, void* d_ws, size_t ws_size,
                              hipStream_t stream) {
  const float* x = (const float*)d_in[0];
  const int* ei = (const int*)d_in[1];
  const int N = in_sizes[0] / 128;
  const int E = in_sizes[1] / 2;
  const int* src = ei;
  const int* dst = ei + E;

  const float* w1 = (const float*)d_in[2];  const float* b1 = (const float*)d_in[3];
  const float* w2 = (const float*)d_in[4];  const float* b2 = (const float*)d_in[5];
  const float* w3 = (const float*)d_in[6];  const float* b3 = (const float*)d_in[7];
  const float* w4 = (const float*)d_in[8];  const float* b4 = (const float*)d_in[9];
  const float* w5 = (const float*)d_in[10]; const float* b5 = (const float*)d_in[11];
  const float* g1 = (const float*)d_in[12]; const float* be1 = (const float*)d_in[13];
  const float* m1 = (const float*)d_in[14]; const float* v1 = (const float*)d_in[15];
  const float* g2 = (const float*)d_in[16]; const float* be2 = (const float*)d_in[17];
  const float* m2 = (const float*)d_in[18]; const float* v2 = (const float*)d_in[19];
  const float* g3 = (const float*)d_in[20]; const float* be3 = (const float*)d_in[21];
  const float* m3 = (const float*)d_in[22]; const float* v3 = (const float*)d_in[23];
  const float* g4 = (const float*)d_in[24]; const float* be4 = (const float*)d_in[25];
  const float* m4 = (const float*)d_in[26]; const float* v4 = (const float*)d_in[27];
  float* out = (float*)d_out;

  char* ws = (char*)d_ws;
  size_t off = 0;
  auto alloc = [&](size_t bytes) -> void* {
    void* p = ws + off;
    off += (bytes + 255) & ~(size_t)255;
    return p;
  };
  const int K = (N + BK_NODES - 1) >> BK_SHIFT;  // 391 for N=100000
  float*        dinv   = (float*)alloc((size_t)N * 4);
  int*          rowptr = (int*)alloc((size_t)N * 4);
  int*          rowend = (int*)alloc((size_t)N * 4);
  int*          colidx = (int*)alloc(((size_t)E + (size_t)(K + 1) * BK_SLACK) * 4);
  unsigned int* pairs  = (unsigned int*)alloc((size_t)E * 4);
  int*          histG  = (int*)alloc((size_t)KMAX * G_SC * 4);
  int*          offs   = (int*)alloc((size_t)KMAX * G_SC * 4);
  int*          btot   = (int*)alloc(KMAX * 4);
  int*          bbase  = (int*)alloc((KMAX + 1) * 4);
  _Float16*     wp1    = (_Float16*)alloc(128 * 64 * 2);
  _Float16*     wp2    = (_Float16*)alloc(64 * 128 * 2);
  _Float16*     wp3    = (_Float16*)alloc(128 * 64 * 2);
  _Float16*     wp4    = (_Float16*)alloc(64 * 32 * 2);
  _Float16*     wp5    = (_Float16*)alloc(32 * 16 * 2);
  __half*       bufA   = (__half*)alloc((size_t)(N + 64) * 128 * 2);
  __half*       bufB   = (__half*)alloc((size_t)(N + 64) * 128 * 2);
  (void)ws_size; (void)n_in; (void)out_size;

  const int chunk = (E + G_SC - 1) / G_SC;

  // CSR build (padded colidx; no global atomic hotspots)
  k_zero_int<<<2, TPB, 0, stream>>>(btot, KMAX);
  k_hist<<<G_SC, TPB, 0, stream>>>(dst, histG, btot, E, K, chunk);
  k_bbase<<<1, KMAX, 0, stream>>>(btot, bbase, K);
  k_offs<<<K, G_SC, 0, stream>>>(histG, bbase, offs);
  k_scatter<<<G_SC, TPB, 0, stream>>>(src, dst, offs, pairs, E, K, chunk);
  k_bucket_sort<<<K, TPB, 0, stream>>>(pairs, bbase, rowptr, rowend, colidx, dinv, N, E);

  // pack weights + zero bufA's F=64 sentinel row
  k_packAll<<<(27144 + TPB - 1) / TPB, TPB, 0, stream>>>(w1, wp1, w2, wp2, w3, wp3, w4, wp4, w5, wp5, bufA, N);

  int gRow = (N + 63) / 64;
  // L1: MFMA GEMM(128->64)*dinv, AGG(64)+BN+ReLU emit *dinv for L2's agg
  k_mgemm<128, 64, 0, true><<<gRow, TPB, 0, stream>>>(x, wp1, dinv, nullptr, nullptr, nullptr, nullptr, nullptr, bufB, N);
  k_agg<64, 2, __half><<<(N + 31) / 32, TPB, 0, stream>>>(bufB, rowptr, rowend, colidx, dinv, b1, g1, be1, m1, v1, bufA, N);
  // L2: AGG(64) first, then MFMA GEMM(64->128)+bias+BN+ReLU
  k_agg<64, 3, __half><<<(N + 31) / 32, TPB, 0, stream>>>(bufA, rowptr, rowend, colidx, dinv, nullptr, nullptr, nullptr, nullptr, nullptr, bufB, N);
  k_mgemm<64, 128, 1, false><<<gRow, TPB, 0, stream>>>(bufB, wp2, nullptr, b2, g2, be2, m2, v2, bufA, N);
  // L3
  k_mgemm<128, 64, 0, false><<<gRow, TPB, 0, stream>>>(bufA, wp3, dinv, nullptr, nullptr, nullptr, nullptr, nullptr, bufB, N);
  k_agg<64, 1, __half><<<(N + 31) / 32, TPB, 0, stream>>>(bufB, rowptr, rowend, colidx, dinv, b3, g3, be3, m3, v3, bufA, N);
  // L4
  k_mgemm<64, 32, 0, false><<<gRow, TPB, 0, stream>>>(bufA, wp4, dinv, nullptr, nullptr, nullptr, nullptr, nullptr, bufB, N);
  k_agg<32, 1, __half><<<(N + 63) / 64, TPB, 0, stream>>>(bufB, rowptr, rowend, colidx, dinv, b4, g4, be4, m4, v4, bufA, N);
  // L5 -> f32 out
  k_mgemm<32, 16, 0, false><<<gRow, TPB, 0, stream>>>(bufA, wp5, dinv, nullptr, nullptr, nullptr, nullptr, nullptr, bufB, N);
  k_agg<16, 0, float><<<(N + 127) / 128, TPB, 0, stream>>>(bufB, rowptr, rowend, colidx, dinv, b5, nullptr, nullptr, nullptr, nullptr, out, N);
}

// Round 8
// 360.368 us; speedup vs baseline: 2.5312x; 1.0096x over previous
//
#include <hip/hip_runtime.h>
#include <hip/hip_fp16.h>

#define BEPS 1e-5f
static constexpr int TPB = 256;
static constexpr int G_SC = 512;      // scatter workgroups
static constexpr int BK_SHIFT = 8;    // bucket = 256-node range
static constexpr int BK_NODES = 256;
static constexpr int KMAX = 512;      // max buckets (N <= 131072)
static constexpr int BK_SLACK = 2048; // per-bucket colidx padding slack

union F4H8 { float4 f4; __half2 h2[4]; };  // 16B = 8 halfs

typedef _Float16 half8 __attribute__((ext_vector_type(8)));
typedef float floatx4 __attribute__((ext_vector_type(4)));

// ================= CSR build: two-level bucket counting sort =================

__global__ __launch_bounds__(TPB) void k_zero_int(int* __restrict__ p, int n) {
  int i = blockIdx.x * TPB + threadIdx.x;
  if (i < n) p[i] = 0;
}

__global__ __launch_bounds__(TPB) void k_hist(const int* __restrict__ dst,
                                              int* __restrict__ histG,
                                              int* __restrict__ btot,
                                              int E, int K, int chunk) {
  __shared__ int lh[KMAX];
  int g = blockIdx.x, t = threadIdx.x;
  for (int i = t; i < KMAX; i += TPB) lh[i] = 0;
  __syncthreads();
  int e0 = g * chunk, e1 = min(E, e0 + chunk);
  for (int e = e0 + t; e < e1; e += TPB) atomicAdd(&lh[dst[e] >> BK_SHIFT], 1);
  __syncthreads();
  for (int i = t; i < K; i += TPB) {
    histG[i * G_SC + g] = lh[i];
    atomicAdd(&btot[i], lh[i]);
  }
}

__global__ __launch_bounds__(KMAX) void k_bbase(const int* __restrict__ btot,
                                                int* __restrict__ bbase, int K) {
  __shared__ int sh[KMAX];
  int t = threadIdx.x;
  int v = (t < K) ? btot[t] : 0;
  sh[t] = v;
  __syncthreads();
  for (int s = 1; s < KMAX; s <<= 1) {
    int x = sh[t];
    int y = (t >= s) ? sh[t - s] : 0;
    __syncthreads();
    sh[t] = x + y;
    __syncthreads();
  }
  if (t < K) bbase[t] = sh[t] - v;
  if (t == 0) bbase[K] = sh[K - 1];
}

__global__ __launch_bounds__(G_SC) void k_offs(const int* __restrict__ histG,
                                               const int* __restrict__ bbase,
                                               int* __restrict__ offs) {
  __shared__ int sh[G_SC];
  int b = blockIdx.x, t = threadIdx.x;
  int v = histG[b * G_SC + t];
  sh[t] = v;
  __syncthreads();
  for (int s = 1; s < G_SC; s <<= 1) {
    int x = sh[t];
    int y = (t >= s) ? sh[t - s] : 0;
    __syncthreads();
    sh[t] = x + y;
    __syncthreads();
  }
  offs[b * G_SC + t] = bbase[b] + sh[t] - v;
}

__global__ __launch_bounds__(TPB) void k_scatter(const int* __restrict__ src,
                                                 const int* __restrict__ dst,
                                                 const int* __restrict__ offs,
                                                 unsigned int* __restrict__ pairs,
                                                 int E, int K, int chunk) {
  __shared__ int cur[KMAX];
  int g = blockIdx.x, t = threadIdx.x;
  for (int i = t; i < K; i += TPB) cur[i] = offs[i * G_SC + g];
  __syncthreads();
  int e0 = g * chunk, e1 = min(E, e0 + chunk);
  for (int e = e0 + t; e < e1; e += TPB) {
    int d = dst[e];
    int b = d >> BK_SHIFT;
    int pos = atomicAdd(&cur[b], 1);
    pairs[pos] = (unsigned int)src[e] | ((unsigned int)(d & (BK_NODES - 1)) << 20);
  }
}

// per-bucket LDS counting sort -> PADDED colidx (lists padded to multiple of 8
// with sentinel N -> zero row; 8-aligned starts; tail-free agg loops).
__global__ __launch_bounds__(TPB) void k_bucket_sort(const unsigned int* __restrict__ pairs,
                                                     const int* __restrict__ bbase,
                                                     int* __restrict__ rowptr,
                                                     int* __restrict__ rowend,
                                                     int* __restrict__ colidx,
                                                     float* __restrict__ dinv,
                                                     int N, int E) {
  __shared__ int cur[BK_NODES];
  __shared__ int sh[BK_NODES];
  int b = blockIdx.x, t = threadIdx.x;
  int base = bbase[b], end = bbase[b + 1];
  int n0 = b << BK_SHIFT;
  int nNodes = min(BK_NODES, N - n0);
  cur[t] = 0;
  __syncthreads();
  for (int e = base + t; e < end; e += TPB) atomicAdd(&cur[pairs[e] >> 20], 1);
  __syncthreads();
  int v = cur[t];                 // raw degree
  int pd = (v + 7) & ~7;          // padded degree
  sh[t] = pd;
  __syncthreads();
  for (int s = 1; s < TPB; s <<= 1) {
    int x = sh[t];
    int y = (t >= s) ? sh[t - s] : 0;
    __syncthreads();
    sh[t] = x + y;
    __syncthreads();
  }
  int Bb = (base + b * BK_SLACK + 7) & ~7;
  int start = Bb + (sh[t] - pd);
  if (t < nNodes) {
    rowptr[n0 + t] = start;
    rowend[n0 + t] = start + pd;
    dinv[n0 + t] = rsqrtf((float)(v + 1));
    for (int i = start + v; i < start + pd; ++i) colidx[i] = N;  // pads -> zero row
  }
  __syncthreads();
  cur[t] = start;
  __syncthreads();
  for (int e = base + t; e < end; e += TPB) {
    unsigned int p = pairs[e];
    int pos = atomicAdd(&cur[p >> 20], 1);
    colidx[pos] = (int)(p & 0xFFFFFu);
  }
}

// ================= W pack (all 5 weights) + bufA zero-row init =================
__device__ inline void packone(const float* __restrict__ W, _Float16* __restrict__ Wp,
                               int i, int FO) {
  int j = i & 7, lane = (i >> 3) & 63, tile = i >> 9;
  int nct = FO >> 4, ct = tile % nct, kch = tile / nct;
  int k = kch * 32 + ((lane >> 4) << 3) + j;
  int n = (ct << 4) + (lane & 15);
  Wp[i] = (_Float16)W[k * FO + n];
}

__global__ __launch_bounds__(TPB) void k_packAll(const float* w1, _Float16* p1,
                                                 const float* w2, _Float16* p2,
                                                 const float* w3, _Float16* p3,
                                                 const float* w4, _Float16* p4,
                                                 const float* w5, _Float16* p5,
                                                 __half* bufA, int N) {
  int i = blockIdx.x * TPB + threadIdx.x;
  if (i < 8192) packone(w1, p1, i, 64);
  else if (i < 16384) packone(w2, p2, i - 8192, 128);
  else if (i < 24576) packone(w3, p3, i - 16384, 64);
  else if (i < 26624) packone(w4, p4, i - 24576, 32);
  else if (i < 27136) packone(w5, p5, i - 26624, 16);
  else if (i < 27144) {  // zero bufA's F=64 sentinel row N
    float4 z = {0.f, 0.f, 0.f, 0.f};
    reinterpret_cast<float4*>(bufA + (size_t)64 * N)[i - 27136] = z;
  }
}

// ================= MFMA GEMM =================
// Rows >= N written as zero (EPI 0, dinv=0) to maintain the sentinel row.
template <int FI, int FO, int EPI, bool F32IN>
__global__ __launch_bounds__(TPB) void k_mgemm(const void* __restrict__ hin,
                                               const _Float16* __restrict__ Wp,
                                               const float* __restrict__ dinv,
                                               const float* __restrict__ bias,
                                               const float* __restrict__ g,
                                               const float* __restrict__ be,
                                               const float* __restrict__ m,
                                               const float* __restrict__ v,
                                               __half* __restrict__ out, int N) {
  constexpr int NCT = FO / 16;
  constexpr int NKC = FI / 32;
  __shared__ float4 Wsh[NKC * NCT * 64];
  for (int i = threadIdx.x; i < NKC * NCT * 64; i += TPB)
    Wsh[i] = reinterpret_cast<const float4*>(Wp)[i];
  __syncthreads();

  int lane = threadIdx.x & 63;
  int wv = threadIdx.x >> 6;
  int quad = lane >> 4;
  int rowBase = blockIdx.x * 64 + wv * 16;
  int rA = min(rowBase + (lane & 15), N - 1);

  floatx4 acc[NCT];
#pragma unroll
  for (int ct = 0; ct < NCT; ++ct) acc[ct] = (floatx4){0.f, 0.f, 0.f, 0.f};

#pragma unroll
  for (int kch = 0; kch < NKC; ++kch) {
    half8 a;
    if constexpr (F32IN) {
      const float4* xp = reinterpret_cast<const float4*>(hin);
      size_t idx = ((size_t)rA * FI + kch * 32 + quad * 8) >> 2;
      float4 fa = xp[idx], fb = xp[idx + 1];
      a[0] = (_Float16)fa.x; a[1] = (_Float16)fa.y; a[2] = (_Float16)fa.z; a[3] = (_Float16)fa.w;
      a[4] = (_Float16)fb.x; a[5] = (_Float16)fb.y; a[6] = (_Float16)fb.z; a[7] = (_Float16)fb.w;
    } else {
      union { float4 f4; half8 h8; } ua;
      ua.f4 = reinterpret_cast<const float4*>(hin)[((size_t)rA * FI + kch * 32 + quad * 8) >> 3];
      a = ua.h8;
    }
#pragma unroll
    for (int ct = 0; ct < NCT; ++ct) {
      union { float4 f4; half8 h8; } ub;
      ub.f4 = Wsh[(kch * NCT + ct) * 64 + lane];
      acc[ct] = __builtin_amdgcn_mfma_f32_16x16x32_f16(a, ub.h8, acc[ct], 0, 0, 0);
    }
  }

  int r0 = rowBase + quad * 4;
  if (EPI == 0) {
    float dv[4];
#pragma unroll
    for (int reg = 0; reg < 4; ++reg) dv[reg] = (r0 + reg < N) ? dinv[r0 + reg] : 0.f;
#pragma unroll
    for (int ct = 0; ct < NCT; ++ct) {
      int col = ct * 16 + (lane & 15);
#pragma unroll
      for (int reg = 0; reg < 4; ++reg) {
        int r = r0 + reg;
        out[(size_t)r * FO + col] = __float2half(acc[ct][reg] * dv[reg]);
      }
    }
  } else {
#pragma unroll
    for (int ct = 0; ct < NCT; ++ct) {
      int col = ct * 16 + (lane & 15);
      float sc = g[col] * rsqrtf(v[col] + BEPS);
      float bb = bias[col] - m[col];
      float ee = be[col];
#pragma unroll
      for (int reg = 0; reg < 4; ++reg) {
        int r = r0 + reg;
        out[(size_t)r * FO + col] = __float2half(fmaxf((acc[ct][reg] + bb) * sc + ee, 0.f));
      }
    }
  }
}

// ========== Fused L2 GEMM chain: h3 = (relu(bn(h2@W2)) @ W3) * dinv ==========
// Row-local chain (agg2 out -> 64->128 BN/ReLU -> 128->64). h2 round-trips
// C-layout -> wave-private LDS (pitch 136 halfs, 16B rows) -> A-fragments;
// no barrier needed (same-wave ds ordering via lgkmcnt). h2 passes through
// fp16 exactly like the old bufA store, so numerics are unchanged.
__global__ __launch_bounds__(TPB) void k_mgemm23(const __half* __restrict__ hin,
                                                 const _Float16* __restrict__ W2p,
                                                 const _Float16* __restrict__ W3p,
                                                 const float* __restrict__ dinv,
                                                 const float* __restrict__ b2,
                                                 const float* __restrict__ g2,
                                                 const float* __restrict__ be2,
                                                 const float* __restrict__ m2,
                                                 const float* __restrict__ v2,
                                                 __half* __restrict__ out, int N) {
  __shared__ float4 W2s[2 * 8 * 64];       // 16 KB  (64->128)
  __shared__ float4 W3s[4 * 4 * 64];       // 16 KB  (128->64)
  __shared__ _Float16 tr[4 * 16 * 136];    // 17 KB  transpose staging
  for (int i = threadIdx.x; i < 1024; i += TPB) W2s[i] = reinterpret_cast<const float4*>(W2p)[i];
  for (int i = threadIdx.x; i < 1024; i += TPB) W3s[i] = reinterpret_cast<const float4*>(W3p)[i];
  __syncthreads();

  int lane = threadIdx.x & 63;
  int wv = threadIdx.x >> 6;
  int quad = lane >> 4;
  int m = lane & 15;
  int rowBase = blockIdx.x * 64 + wv * 16;
  int rA = min(rowBase + m, N - 1);

  // step 1: 64 -> 128
  floatx4 acc1[8];
#pragma unroll
  for (int ct = 0; ct < 8; ++ct) acc1[ct] = (floatx4){0.f, 0.f, 0.f, 0.f};
#pragma unroll
  for (int kch = 0; kch < 2; ++kch) {
    union { float4 f4; half8 h8; } ua;
    ua.f4 = reinterpret_cast<const float4*>(hin)[((size_t)rA * 64 + kch * 32 + quad * 8) >> 3];
#pragma unroll
    for (int ct = 0; ct < 8; ++ct) {
      union { float4 f4; half8 h8; } ub;
      ub.f4 = W2s[(kch * 8 + ct) * 64 + lane];
      acc1[ct] = __builtin_amdgcn_mfma_f32_16x16x32_f16(ua.h8, ub.h8, acc1[ct], 0, 0, 0);
    }
  }
  // BN+ReLU -> fp16 -> wave-private LDS (C layout: col=ct*16+m, row=quad*4+reg)
  _Float16* mytr = tr + wv * 16 * 136;
#pragma unroll
  for (int ct = 0; ct < 8; ++ct) {
    int col = ct * 16 + m;
    float sc = g2[col] * rsqrtf(v2[col] + BEPS);
    float bb = b2[col] - m2[col];
    float ee = be2[col];
#pragma unroll
    for (int reg = 0; reg < 4; ++reg) {
      int r = quad * 4 + reg;
      mytr[r * 136 + col] = (_Float16)fmaxf((acc1[ct][reg] + bb) * sc + ee, 0.f);
    }
  }
  // step 2: 128 -> 64 (A-frag: row=m, k=kch*32+quad*8+j)
  floatx4 acc2[4];
#pragma unroll
  for (int ct = 0; ct < 4; ++ct) acc2[ct] = (floatx4){0.f, 0.f, 0.f, 0.f};
#pragma unroll
  for (int kch = 0; kch < 4; ++kch) {
    half8 a2 = *reinterpret_cast<const half8*>(&mytr[m * 136 + kch * 32 + quad * 8]);
#pragma unroll
    for (int ct = 0; ct < 4; ++ct) {
      union { float4 f4; half8 h8; } ub;
      ub.f4 = W3s[(kch * 4 + ct) * 64 + lane];
      acc2[ct] = __builtin_amdgcn_mfma_f32_16x16x32_f16(a2, ub.h8, acc2[ct], 0, 0, 0);
    }
  }
  int r0 = rowBase + quad * 4;
  float dv[4];
#pragma unroll
  for (int reg = 0; reg < 4; ++reg) dv[reg] = (r0 + reg < N) ? dinv[r0 + reg] : 0.f;
#pragma unroll
  for (int ct = 0; ct < 4; ++ct) {
    int col = ct * 16 + m;
#pragma unroll
    for (int reg = 0; reg < 4; ++reg) {
      int r = r0 + reg;
      out[(size_t)r * 64 + col] = __float2half(acc2[ct][reg] * dv[reg]);
    }
  }
}

// ================= Aggregation (fp16 in, f32 accumulate) =================
// Padded CSR; main loop = 16 gathers in flight (R8: was 8 -> latency-bound at
// 33% hbm, R6 PMC), tail = at most one 8-chunk (pd % 8 == 0).
// MODE 0: val+bias (TO=float, final)  MODE 1: relu(bn(val+bias))
// MODE 2: relu(bn(val+bias))*dinv     MODE 3: val (pre-GEMM agg)
template <int F, int MODE, typename TO>
__global__ __launch_bounds__(TPB) void k_agg(const __half* __restrict__ in,
                                             const int* __restrict__ rowptr,
                                             const int* __restrict__ rowend,
                                             const int* __restrict__ colidx,
                                             const float* __restrict__ dinv,
                                             const float* __restrict__ bias,
                                             const float* __restrict__ g,
                                             const float* __restrict__ be,
                                             const float* __restrict__ m,
                                             const float* __restrict__ v,
                                             TO* __restrict__ out, int N) {
  constexpr int V = F / 8;
  constexpr int NPB = TPB / V;
  int node = blockIdx.x * NPB + (int)(threadIdx.x / V);
  int lane = threadIdx.x % V;
  if (node >= N) return;
  const float4* in16 = reinterpret_cast<const float4*>(in);
  const size_t rs = F / 8;
  float acc[8];
  {
    F4H8 u;
    u.f4 = in16[(size_t)node * rs + lane];
#pragma unroll
    for (int i = 0; i < 4; ++i) {
      float2 t2 = __half22float2(u.h2[i]);
      acc[2 * i] = t2.x;
      acc[2 * i + 1] = t2.y;
    }
  }
  int e0 = rowptr[node], e1 = rowend[node];
  int e = e0;
  for (; e + 16 <= e1; e += 16) {
    int4 c0 = *reinterpret_cast<const int4*>(colidx + e);
    int4 c1 = *reinterpret_cast<const int4*>(colidx + e + 4);
    int4 c2 = *reinterpret_cast<const int4*>(colidx + e + 8);
    int4 c3 = *reinterpret_cast<const int4*>(colidx + e + 12);
    F4H8 u[16];
    u[0].f4  = in16[(size_t)c0.x * rs + lane];
    u[1].f4  = in16[(size_t)c0.y * rs + lane];
    u[2].f4  = in16[(size_t)c0.z * rs + lane];
    u[3].f4  = in16[(size_t)c0.w * rs + lane];
    u[4].f4  = in16[(size_t)c1.x * rs + lane];
    u[5].f4  = in16[(size_t)c1.y * rs + lane];
    u[6].f4  = in16[(size_t)c1.z * rs + lane];
    u[7].f4  = in16[(size_t)c1.w * rs + lane];
    u[8].f4  = in16[(size_t)c2.x * rs + lane];
    u[9].f4  = in16[(size_t)c2.y * rs + lane];
    u[10].f4 = in16[(size_t)c2.z * rs + lane];
    u[11].f4 = in16[(size_t)c2.w * rs + lane];
    u[12].f4 = in16[(size_t)c3.x * rs + lane];
    u[13].f4 = in16[(size_t)c3.y * rs + lane];
    u[14].f4 = in16[(size_t)c3.z * rs + lane];
    u[15].f4 = in16[(size_t)c3.w * rs + lane];
#pragma unroll
    for (int q = 0; q < 16; ++q) {
#pragma unroll
      for (int i = 0; i < 4; ++i) {
        float2 t2 = __half22float2(u[q].h2[i]);
        acc[2 * i] += t2.x;
        acc[2 * i + 1] += t2.y;
      }
    }
  }
  if (e < e1) {  // exactly one 8-chunk (pd % 8 == 0)
    int4 c0 = *reinterpret_cast<const int4*>(colidx + e);
    int4 c1 = *reinterpret_cast<const int4*>(colidx + e + 4);
    F4H8 u[8];
    u[0].f4 = in16[(size_t)c0.x * rs + lane];
    u[1].f4 = in16[(size_t)c0.y * rs + lane];
    u[2].f4 = in16[(size_t)c0.z * rs + lane];
    u[3].f4 = in16[(size_t)c0.w * rs + lane];
    u[4].f4 = in16[(size_t)c1.x * rs + lane];
    u[5].f4 = in16[(size_t)c1.y * rs + lane];
    u[6].f4 = in16[(size_t)c1.z * rs + lane];
    u[7].f4 = in16[(size_t)c1.w * rs + lane];
#pragma unroll
    for (int q = 0; q < 8; ++q) {
#pragma unroll
      for (int i = 0; i < 4; ++i) {
        float2 t2 = __half22float2(u[q].h2[i]);
        acc[2 * i] += t2.x;
        acc[2 * i + 1] += t2.y;
      }
    }
  }
  float dv = dinv[node];
#pragma unroll
  for (int i = 0; i < 8; ++i) acc[i] *= dv;
  if (MODE == 0) {
    float4 ba = reinterpret_cast<const float4*>(bias)[lane * 2];
    float4 bb = reinterpret_cast<const float4*>(bias)[lane * 2 + 1];
    acc[0] += ba.x; acc[1] += ba.y; acc[2] += ba.z; acc[3] += ba.w;
    acc[4] += bb.x; acc[5] += bb.y; acc[6] += bb.z; acc[7] += bb.w;
  } else if (MODE == 1 || MODE == 2) {
    const float4* B = reinterpret_cast<const float4*>(bias);
    const float4* G = reinterpret_cast<const float4*>(g);
    const float4* Be = reinterpret_cast<const float4*>(be);
    const float4* M = reinterpret_cast<const float4*>(m);
    const float4* Vv = reinterpret_cast<const float4*>(v);
#pragma unroll
    for (int h = 0; h < 2; ++h) {
      float4 b4 = B[lane * 2 + h], g4 = G[lane * 2 + h], e4 = Be[lane * 2 + h];
      float4 m4 = M[lane * 2 + h], v4 = Vv[lane * 2 + h];
      float* a = acc + 4 * h;
      a[0] = fmaxf((a[0] + b4.x - m4.x) * (g4.x * rsqrtf(v4.x + BEPS)) + e4.x, 0.f);
      a[1] = fmaxf((a[1] + b4.y - m4.y) * (g4.y * rsqrtf(v4.y + BEPS)) + e4.y, 0.f);
      a[2] = fmaxf((a[2] + b4.z - m4.z) * (g4.z * rsqrtf(v4.z + BEPS)) + e4.z, 0.f);
      a[3] = fmaxf((a[3] + b4.w - m4.w) * (g4.w * rsqrtf(v4.w + BEPS)) + e4.w, 0.f);
    }
    if (MODE == 2) {
#pragma unroll
      for (int i = 0; i < 8; ++i) acc[i] *= dv;
    }
  }
  if constexpr (sizeof(TO) == 2) {
    F4H8 u;
#pragma unroll
    for (int i = 0; i < 4; ++i) u.h2[i] = __floats2half2_rn(acc[2 * i], acc[2 * i + 1]);
    reinterpret_cast<float4*>(out)[(size_t)node * rs + lane] = u.f4;
  } else {
    float4 o0 = {acc[0], acc[1], acc[2], acc[3]};
    float4 o1 = {acc[4], acc[5], acc[6], acc[7]};
    float4* op = reinterpret_cast<float4*>((float*)out + (size_t)node * F + lane * 8);
    op[0] = o0;
    op[1] = o1;
  }
}

// ================= launch =================

extern "C" void kernel_launch(void* const* d_in, const int* in_sizes, int n_in,
                              void* d_out, int out_size, void* d_ws, size_t ws_size,
                              hipStream_t stream) {
  const float* x = (const float*)d_in[0];
  const int* ei = (const int*)d_in[1];
  const int N = in_sizes[0] / 128;
  const int E = in_sizes[1] / 2;
  const int* src = ei;
  const int* dst = ei + E;

  const float* w1 = (const float*)d_in[2];  const float* b1 = (const float*)d_in[3];
  const float* w2 = (const float*)d_in[4];  const float* b2 = (const float*)d_in[5];
  const float* w3 = (const float*)d_in[6];  const float* b3 = (const float*)d_in[7];
  const float* w4 = (const float*)d_in[8];  const float* b4 = (const float*)d_in[9];
  const float* w5 = (const float*)d_in[10]; const float* b5 = (const float*)d_in[11];
  const float* g1 = (const float*)d_in[12]; const float* be1 = (const float*)d_in[13];
  const float* m1 = (const float*)d_in[14]; const float* v1 = (const float*)d_in[15];
  const float* g2 = (const float*)d_in[16]; const float* be2 = (const float*)d_in[17];
  const float* m2 = (const float*)d_in[18]; const float* v2 = (const float*)d_in[19];
  const float* g3 = (const float*)d_in[20]; const float* be3 = (const float*)d_in[21];
  const float* m3 = (const float*)d_in[22]; const float* v3 = (const float*)d_in[23];
  const float* g4 = (const float*)d_in[24]; const float* be4 = (const float*)d_in[25];
  const float* m4 = (const float*)d_in[26]; const float* v4 = (const float*)d_in[27];
  float* out = (float*)d_out;

  char* ws = (char*)d_ws;
  size_t off = 0;
  auto alloc = [&](size_t bytes) -> void* {
    void* p = ws + off;
    off += (bytes + 255) & ~(size_t)255;
    return p;
  };
  const int K = (N + BK_NODES - 1) >> BK_SHIFT;  // 391 for N=100000
  float*        dinv   = (float*)alloc((size_t)N * 4);
  int*          rowptr = (int*)alloc((size_t)N * 4);
  int*          rowend = (int*)alloc((size_t)N * 4);
  int*          colidx = (int*)alloc(((size_t)E + (size_t)(K + 1) * BK_SLACK) * 4);
  unsigned int* pairs  = (unsigned int*)alloc((size_t)E * 4);
  int*          histG  = (int*)alloc((size_t)KMAX * G_SC * 4);
  int*          offs   = (int*)alloc((size_t)KMAX * G_SC * 4);
  int*          btot   = (int*)alloc(KMAX * 4);
  int*          bbase  = (int*)alloc((KMAX + 1) * 4);
  _Float16*     wp1    = (_Float16*)alloc(128 * 64 * 2);
  _Float16*     wp2    = (_Float16*)alloc(64 * 128 * 2);
  _Float16*     wp3    = (_Float16*)alloc(128 * 64 * 2);
  _Float16*     wp4    = (_Float16*)alloc(64 * 32 * 2);
  _Float16*     wp5    = (_Float16*)alloc(32 * 16 * 2);
  __half*       bufA   = (__half*)alloc((size_t)(N + 64) * 128 * 2);
  __half*       bufB   = (__half*)alloc((size_t)(N + 64) * 128 * 2);
  (void)ws_size; (void)n_in; (void)out_size;

  const int chunk = (E + G_SC - 1) / G_SC;

  // CSR build (padded colidx; no global atomic hotspots)
  k_zero_int<<<2, TPB, 0, stream>>>(btot, KMAX);
  k_hist<<<G_SC, TPB, 0, stream>>>(dst, histG, btot, E, K, chunk);
  k_bbase<<<1, KMAX, 0, stream>>>(btot, bbase, K);
  k_offs<<<K, G_SC, 0, stream>>>(histG, bbase, offs);
  k_scatter<<<G_SC, TPB, 0, stream>>>(src, dst, offs, pairs, E, K, chunk);
  k_bucket_sort<<<K, TPB, 0, stream>>>(pairs, bbase, rowptr, rowend, colidx, dinv, N, E);

  // pack weights + zero bufA's F=64 sentinel row
  k_packAll<<<(27144 + TPB - 1) / TPB, TPB, 0, stream>>>(w1, wp1, w2, wp2, w3, wp3, w4, wp4, w5, wp5, bufA, N);

  int gRow = (N + 63) / 64;
  // L1: MFMA GEMM(128->64)*dinv, AGG(64)+BN+ReLU emit *dinv for L2's agg
  k_mgemm<128, 64, 0, true><<<gRow, TPB, 0, stream>>>(x, wp1, dinv, nullptr, nullptr, nullptr, nullptr, nullptr, bufB, N);
  k_agg<64, 2, __half><<<(N + 31) / 32, TPB, 0, stream>>>(bufB, rowptr, rowend, colidx, dinv, b1, g1, be1, m1, v1, bufA, N);
  // L2+L3 head: AGG(64), then fused GEMM chain 64->128(BN,ReLU)->64 (*dinv)
  k_agg<64, 3, __half><<<(N + 31) / 32, TPB, 0, stream>>>(bufA, rowptr, rowend, colidx, dinv, nullptr, nullptr, nullptr, nullptr, nullptr, bufB, N);
  k_mgemm23<<<gRow, TPB, 0, stream>>>(bufB, wp2, wp3, dinv, b2, g2, be2, m2, v2, bufA, N);
  // L3 agg
  k_agg<64, 1, __half><<<(N + 31) / 32, TPB, 0, stream>>>(bufA, rowptr, rowend, colidx, dinv, b3, g3, be3, m3, v3, bufB, N);
  // L4
  k_mgemm<64, 32, 0, false><<<gRow, TPB, 0, stream>>>(bufB, wp4, dinv, nullptr, nullptr, nullptr, nullptr, nullptr, bufA, N);
  k_agg<32, 1, __half><<<(N + 63) / 64, TPB, 0, stream>>>(bufA, rowptr, rowend, colidx, dinv, b4, g4, be4, m4, v4, bufB, N);
  // L5 -> f32 out
  k_mgemm<32, 16, 0, false><<<gRow, TPB, 0, stream>>>(bufB, wp5, dinv, nullptr, nullptr, nullptr, nullptr, nullptr, bufA, N);
  k_agg<16, 0, float><<<(N + 127) / 128, TPB, 0, stream>>>(bufA, rowptr, rowend, colidx, dinv, b5, nullptr, nullptr, nullptr, nullptr, out, N);
}